// Round 17
// baseline (574.249 us; speedup 1.0000x reference)
//
#include <hip/hip_runtime.h>
#include <stdint.h>

typedef __attribute__((ext_vector_type(8))) short bf16x8;
typedef __attribute__((ext_vector_type(4))) float f32x4;
typedef __attribute__((ext_vector_type(4))) unsigned int u32x4;

#define DEV __device__ __forceinline__

DEV float bf2f(unsigned short u){ union{unsigned int i; float f;} v; v.i=((unsigned int)u)<<16; return v.f; }
DEV unsigned short f2bf(float f){ union{float f; unsigned int i;} v; v.f=f; unsigned int x=v.i;
  return (unsigned short)((x + 0x7fffu + ((x>>16)&1u)) >> 16); }

// ---------------------------------------------------------------------------
// Zero padded-border prefix (th..gt2) + transpose s=4 weights, one launch.
// ---------------------------------------------------------------------------
__global__ void k_zero_wt4(uint4* __restrict__ p, int n16,
                           const float* __restrict__ wp, const float* __restrict__ wg,
                           float* __restrict__ wT)
{
  int nzb = (n16 + 255) >> 8;
  int bid = blockIdx.x;
  if (bid < nzb) {
    int idx = bid*256 + threadIdx.x;
    if (idx < n16) p[idx] = uint4{0,0,0,0};
  } else {
    int idx = (bid - nzb)*256 + threadIdx.x;
    if (idx < 1024*32) {
      int k = idx >> 5, c = idx & 31;
      int cc = k >> 4, ksp = k & 15;
      wT[idx] = (c < 16) ? wp[(c*64+cc)*16 + ksp] : wg[((c-16)*64+cc)*16 + ksp];
    }
  }
}

// ---------------------------------------------------------------------------
// prep bodies (shared LDS buffer, routed by block range in k_prep_all)
// ---------------------------------------------------------------------------
DEV void prep1_body(int bid, const float* __restrict__ x,
                    const float* __restrict__ wt, const float* __restrict__ bt,
                    const float* __restrict__ wp, const float* __restrict__ bp,
                    const float* __restrict__ wg, const float* __restrict__ bg,
                    unsigned short* __restrict__ th, unsigned short* __restrict__ ph,
                    float* __restrict__ gt, char* smemc)
{
  float (*red)[64][48] = (float(*)[64][48])smemc;
  int tid = threadIdx.x;
  int grp = tid >> 6, pixl = tid & 63;
  int pix = bid*64 + pixl;                 // [0, 32768)
  int b = pix >> 14, p = pix & 16383, i = p >> 7, j = p & 127;
  float a[48];
#pragma unroll
  for (int c=0;c<48;++c) a[c]=0.f;
  const float* xb = x + (size_t)b*64*16384 + p;
#pragma unroll
  for (int c4=0; c4<4; ++c4) {
    int cc = grp*16 + c4*4;
    float xv[4];
#pragma unroll
    for (int u=0;u<4;++u) xv[u] = xb[(size_t)(cc+u)*16384];
#pragma unroll
    for (int ic=0;ic<16;++ic) {
      float4 w0 = *(const float4*)(wt + ic*64 + cc);
      float4 w1 = *(const float4*)(wp + ic*64 + cc);
      float4 w2 = *(const float4*)(wg + ic*64 + cc);
      a[ic]    += xv[0]*w0.x + xv[1]*w0.y + xv[2]*w0.z + xv[3]*w0.w;
      a[16+ic] += xv[0]*w1.x + xv[1]*w1.y + xv[2]*w1.z + xv[3]*w1.w;
      a[32+ic] += xv[0]*w2.x + xv[1]*w2.y + xv[2]*w2.z + xv[3]*w2.w;
    }
  }
  if (grp) {
#pragma unroll
    for (int c=0;c<48;++c) red[grp-1][pixl][c] = a[c];
  }
  __syncthreads();
  if (grp == 0) {
#pragma unroll
    for (int c=0;c<48;++c) a[c] += red[0][pixl][c] + red[1][pixl][c] + red[2][pixl][c];
    const float TEMPC = 14.426950408889634f;
    unsigned short o[16];
#pragma unroll
    for (int ic=0;ic<16;++ic) o[ic] = f2bf((a[ic]+bt[ic])*TEMPC);
    uint4* d0 = (uint4*)(th + ((size_t)(b*134 + i+3)*136 + (j+3))*16);
    d0[0]=*(uint4*)&o[0]; d0[1]=*(uint4*)&o[8];
#pragma unroll
    for (int ic=0;ic<16;++ic) o[ic] = f2bf(a[16+ic]+bp[ic]);
    uint4* d1 = (uint4*)(ph + ((size_t)(b*134 + i+3)*136 + (j+3))*16);
    d1[0]=*(uint4*)&o[0]; d1[1]=*(uint4*)&o[8];
#pragma unroll
    for (int ic=0;ic<16;++ic)
      gt[(((size_t)b*16+ic)*134 + i+3)*136 + (j+3)] = a[32+ic]+bg[ic];
  }
}

DEV void conv2_body(int bid, const float* __restrict__ x,
                    const float* __restrict__ wp, const float* __restrict__ bp,
                    const float* __restrict__ wg, const float* __restrict__ bg,
                    unsigned short* __restrict__ phi, float* __restrict__ gt, char* smemc)
{
  float (*red)[64][32] = (float(*)[64][32])smemc;
  int tid = threadIdx.x;
  int grp = tid >> 6, pixl = tid & 63;
  int pix = bid*64 + pixl;                 // [0, 8192)
  int b = pix >> 12, p = pix & 4095, i = p >> 6, j = p & 63;
  float a[32];
#pragma unroll
  for (int c=0;c<32;++c) a[c]=0.f;
  const float* xb = x + (size_t)b*64*16384 + (i*2)*128 + j*2;
#pragma unroll
  for (int c0=0; c0<16; ++c0) {
    int cc = grp*16 + c0;
    const float* xp = xb + (size_t)cc*16384;
    float xv[4];
    xv[0]=xp[0]; xv[1]=xp[1]; xv[2]=xp[128]; xv[3]=xp[129];
#pragma unroll
    for (int ic=0;ic<16;++ic) {
      float4 w0 = *(const float4*)(wp + (ic*64+cc)*4);
      float4 w1 = *(const float4*)(wg + (ic*64+cc)*4);
      a[ic]    += xv[0]*w0.x + xv[1]*w0.y + xv[2]*w0.z + xv[3]*w0.w;
      a[16+ic] += xv[0]*w1.x + xv[1]*w1.y + xv[2]*w1.z + xv[3]*w1.w;
    }
  }
  if (grp) {
#pragma unroll
    for (int c=0;c<32;++c) red[grp-1][pixl][c] = a[c];
  }
  __syncthreads();
  if (grp == 0) {
#pragma unroll
    for (int c=0;c<32;++c) a[c] += red[0][pixl][c] + red[1][pixl][c] + red[2][pixl][c];
    unsigned short o[16];
#pragma unroll
    for (int ic=0;ic<16;++ic) o[ic] = f2bf(a[ic]+bp[ic]);
    uint4* d1 = (uint4*)(phi + ((size_t)(b*70 + i+3)*72 + (j+3))*16);
    d1[0]=*(uint4*)&o[0]; d1[1]=*(uint4*)&o[8];
#pragma unroll
    for (int ic=0;ic<16;++ic)
      gt[(((size_t)b*16+ic)*70 + i+3)*72 + (j+3)] = a[16+ic]+bg[ic];
  }
}

DEV void conv4_body(int bid, const float* __restrict__ x, const float* __restrict__ wT,
                    const float* __restrict__ bp, const float* __restrict__ bg,
                    unsigned short* __restrict__ phi, float* __restrict__ gt, char* smemc)
{
  float (*xs)[1028] = (float(*)[1028])smemc;
  int tid = threadIdx.x;
  int pix0 = bid*8;                        // [0,2048) step 8
  for (int idx = tid; idx < 8*1024; idx += 256) {
    int pl = idx >> 10, e = idx & 1023;
    int pix = pix0 + pl; int b = pix >> 10, p = pix & 1023, i = p >> 5, j = p & 31;
    int cc = e >> 4, a_ = (e >> 2) & 3, bb = e & 3;
    xs[pl][e] = x[(((size_t)b*64+cc)*128 + i*4+a_)*128 + j*4+bb];
  }
  __syncthreads();
  int pp = tid >> 5, icp = tid & 31;
  int pix = pix0 + pp; int b = pix >> 10, p = pix & 1023, i = p >> 5, j = p & 31;
  float acc = 0.f;
#pragma unroll 8
  for (int k4=0; k4<256; ++k4) {
    float4 xv = *(const float4*)(&xs[pp][k4*4]);
    acc += xv.x*wT[(k4*4  )*32+icp] + xv.y*wT[(k4*4+1)*32+icp]
         + xv.z*wT[(k4*4+2)*32+icp] + xv.w*wT[(k4*4+3)*32+icp];
  }
  int ic = icp & 15;
  if (icp < 16)
    phi[(((size_t)(b*38 + i+3)*40) + (j+3))*16 + ic] = f2bf(acc + bp[ic]);
  else
    gt[(((size_t)b*16+ic)*38 + i+3)*40 + (j+3)] = acc + bg[ic];
}

__global__ void k_prep_all(const float* __restrict__ x,
                           const float* __restrict__ wt, const float* __restrict__ bt,
                           const float* __restrict__ wp0, const float* __restrict__ bp0,
                           const float* __restrict__ wg0, const float* __restrict__ bg0,
                           const float* __restrict__ wp1, const float* __restrict__ bp1,
                           const float* __restrict__ wg1, const float* __restrict__ bg1,
                           const float* __restrict__ wT4, const float* __restrict__ bp2,
                           const float* __restrict__ bg2,
                           unsigned short* __restrict__ th, unsigned short* __restrict__ ph0,
                           float* __restrict__ gt0,
                           unsigned short* __restrict__ ph1, float* __restrict__ gt1,
                           unsigned short* __restrict__ ph2, float* __restrict__ gt2)
{
  __shared__ __align__(16) char smem[36864];
  int bid = blockIdx.x;
  if (bid < 512)      prep1_body(bid, x, wt,bt, wp0,bp0, wg0,bg0, th, ph0, gt0, smem);
  else if (bid < 640) conv2_body(bid-512, x, wp1,bp1, wg1,bg1, ph1, gt1, smem);
  else                conv4_body(bid-640, x, wT4, bp2, bg2, ph2, gt2, smem);
}

// ---------------------------------------------------------------------------
// V tile buffer: g8b[b][sh][y][xb][c][32] bf16 (1KB tile per (sh,y,xb)).
// ---------------------------------------------------------------------------
template<int HP, int WX, int HS>
DEV void shift_body(int idx, const float* __restrict__ gt, unsigned short* __restrict__ g8b)
{
  const int XB = HS/32;
  int xkg = idx & 3;
  int c = (idx >> 2) & 15;
  int t = idx >> 6;
  int xb = t % XB; t /= XB;
  int y = t % HP; t /= HP;
  int sh = t & 7; int b = t >> 3;
  const float* src = gt + (((size_t)b*16+c)*HP + y)*WX + xb*32 + xkg*8 + sh;
  unsigned short o[8];
#pragma unroll
  for (int j=0;j<8;++j) o[j] = f2bf(src[j]);
  unsigned short* dst = g8b + ((((size_t)(b*8+sh)*HP + y)*XB + xb)*16 + c)*32 + xkg*8;
  *(uint4*)dst = *(uint4*)&o[0];
}

__global__ void k_shift_all(const float* __restrict__ gt0, const float* __restrict__ gt1,
                            const float* __restrict__ gt2,
                            unsigned short* __restrict__ g80, unsigned short* __restrict__ g81,
                            unsigned short* __restrict__ g82)
{
  const int T0 = 2*8*134*4*16*4;           // 548864
  const int T1 = 2*8*70*2*16*4;            // 143360
  const int T2 = 2*8*38*1*16*4;            // 38912
  int idx = blockIdx.x*256 + threadIdx.x;
  if (idx < T0) { shift_body<134,136,128>(idx, gt0, g80); return; }
  idx -= T0;
  if (idx < T1) { shift_body<70,72,64>(idx, gt1, g81); return; }
  idx -= T1;
  if (idx < T2) { shift_body<38,40,32>(idx, gt2, g82); }
}

// ---------------------------------------------------------------------------
// Flash attention body: fixed shift P=exp2(min(sc-64,120)), Q-tile 32, 8 waves,
// 256 keys/iter. theta staged once into swizzled LDS; phi from global
// (coalesced, streaming); V nontemporal from g8b tiles.
// P DOUBLE-BUFFERED in LDS -> ONE barrier per iteration: next-iter QK loads
// overlap current-iter PV MFMAs (software pipeline).
// accP bf16 nontemporal, permuted coalesced layout (128B stores).
// ---------------------------------------------------------------------------
template<int HS, int LG, int HP, int WX, int CK, int NCH>
DEV void attn_body(int bid, int slot0,
                   const unsigned short* __restrict__ th,
                   const unsigned short* __restrict__ phi,
                   const unsigned short* __restrict__ g8b,
                   unsigned short* __restrict__ accP, float* __restrict__ lP, char* smem)
{
  const int PO = 30464;
  int tid = threadIdx.x;
  int w = tid >> 6, lane = tid & 63, l15 = lane & 15, g = lane >> 4;
  int chunk, b, qt;
  if (NCH == 8) { chunk = bid & 7; b = (bid >> 3) & 1; qt = bid >> 4; }
  else          { chunk = bid & 3; b = (bid >> 2) & 1; qt = bid >> 3; }
  int q0 = qt * 32;
  int slot = slot0 + chunk;

  const char* thB  = (const char*)th  + (size_t)b*134*136*32;
  const char* phiB = (const char*)phi + (size_t)b*HP*WX*32;

  // ---- stage theta window (rows 4qt+2 .. 4qt+8) into swizzled LDS ----
  for (int u = tid; u < 7*136*2; u += 512) {
    int half = u & 1; int cu = (u >> 1) % 136; int r = (u >> 1) / 136;
    uint4 v = *(const uint4*)(thB + (((4*qt+2+r)*136 + cu)*32 + half*16));
    int la = (((r*136 + cu)*32) + half*16) ^ (((cu >> 2) & 7) << 4);
    *(uint4*)(smem + la) = v;
  }
  __syncthreads();

  f32x4 acc[2][7];
#pragma unroll
  for (int rt=0;rt<2;++rt)
#pragma unroll
    for (int et=0;et<7;++et) acc[rt][et] = f32x4{0.f,0.f,0.f,0.f};
  float lacc[2][4];
#pragma unroll
  for (int rt=0;rt<2;++rt)
#pragma unroll
    for (int r=0;r<4;++r) lacc[rt][r] = 0.f;

  const int XBv = HS/32;
  const char* g8B  = (const char*)g8b + (size_t)b*8*HP*XBv*1024;
  const int EPL = HP*XBv*1024;                 // bytes per shift-plane
  int laneVb = l15*64 + g*16;                  // within 1KB tile
  int xrP = (l15 & 7) << 4;                    // P-lds read swizzle
  int colb = 4*l15 + 2;                        // theta col base (a0); a1 = +64
  int hb = (g & 1) << 4;
  const bf16x8 ZV = {0,0,0,0,0,0,0,0};
  const int ITERS = CK/256;
  const float SHIFT = 64.0f, CLAMP = 120.0f;

#pragma unroll 1
  for (int it = 0; it < ITERS; ++it) {
    int k0 = chunk*CK + it*256;
    int po = PO + ((it & 1) << 14);            // P double-buffer
    // ---------------- QK ----------------
    f32x4 sc[2][2];
#pragma unroll
    for (int rt=0;rt<2;++rt){ sc[rt][0]=f32x4{0.f,0.f,0.f,0.f}; sc[rt][1]=f32x4{0.f,0.f,0.f,0.f}; }
    int kr_w = (k0 + w*32) >> LG;
    int kc_w = (w*32) & (HS-1);
    int base0 = (kr_w*WX + kc_w + l15)*32 + hb;
    int base1 = base0 + 512;
#pragma unroll
    for (int ks=0; ks<25; ++ks) {
      int p0 = 2*ks;
      int p1 = (2*ks+1 > 48) ? 48 : 2*ks+1;
      int dr0 = p0/7, dc0 = p0%7;
      int dr1 = p1/7, dc1 = p1%7;
      int c0 = colb + dc0, c1 = colb + dc1;
      int la0 = ((dr0*136 + c0)*32 + hb) ^ (((c0 >> 2) & 7) << 4);
      int la1 = ((dr1*136 + c1)*32 + hb) ^ (((c1 >> 2) & 7) << 4);
      int laA = (g & 2) ? la1 : la0;
      int KB0 = (dr0*WX + dc0)*32;
      int KB1 = (dr1*WX + dc1)*32;
      int selB = (g & 2) ? KB1 : KB0;
      bf16x8 a0 = *(const bf16x8*)(smem + laA);
      bf16x8 a1 = *(const bf16x8*)(smem + laA + 2048);   // +64 cols, same swizzle
      if (ks == 24) {
        bool z = (g & 2) != 0;
        a0 = z ? ZV : a0; a1 = z ? ZV : a1;
      }
      bf16x8 b0 = *(const bf16x8*)(phiB + base0 + selB);
      bf16x8 b1 = *(const bf16x8*)(phiB + base1 + selB);
      sc[0][0] = __builtin_amdgcn_mfma_f32_16x16x32_bf16(a0, b0, sc[0][0], 0,0,0);
      sc[0][1] = __builtin_amdgcn_mfma_f32_16x16x32_bf16(a0, b1, sc[0][1], 0,0,0);
      sc[1][0] = __builtin_amdgcn_mfma_f32_16x16x32_bf16(a1, b0, sc[1][0], 0,0,0);
      sc[1][1] = __builtin_amdgcn_mfma_f32_16x16x32_bf16(a1, b1, sc[1][1], 0,0,0);
    }
    // ---------------- P = exp2(min(S-64,120)), accumulate l, write P_lds ----------------
#pragma unroll
    for (int rt=0;rt<2;++rt) {
#pragma unroll
      for (int r=0;r<4;++r) {
        float pa = __builtin_amdgcn_exp2f(fminf(sc[rt][0][r] - SHIFT, CLAMP));
        float pb = __builtin_amdgcn_exp2f(fminf(sc[rt][1][r] - SHIFT, CLAMP));
        lacc[rt][r] += pa + pb;
        int q_ = rt*16 + g*4 + r;
        int offa = q_*512 + (w*32 + l15)*2;      offa ^= (q_&7)<<4;
        int offb = q_*512 + (w*32 + 16 + l15)*2; offb ^= (q_&7)<<4;
        *(unsigned short*)(smem + po + offa) = f2bf(pa);
        *(unsigned short*)(smem + po + offb) = f2bf(pb);
      }
    }
    __syncthreads();       // single barrier: P[cur] ready; PV[prev] readers done
    // ---------------- PV (overlaps next-iter QK loads) ----------------
    if (w < 7) {
#pragma unroll
      for (int ks2=0; ks2<8; ++ks2) {
        int kk = k0 + ks2*32;
        int krv = kk >> LG;
        int kcb = kk & (HS-1);
        bf16x8 pf[2];
#pragma unroll
        for (int rt=0;rt<2;++rt) {
          int off = (rt*16 + l15)*512 + ks2*64 + g*16;
          off ^= xrP;
          pf[rt] = *(const bf16x8*)(smem + po + off);
        }
        int vb = ((krv + w)*XBv + (kcb >> 5))*1024 + laneVb;
        bf16x8 vf[7];
#pragma unroll
        for (int et=0;et<7;++et) {
          u32x4 t0 = __builtin_nontemporal_load((const u32x4*)(g8B + vb + et*EPL));
          vf[et] = *(bf16x8*)&t0;
        }
        __builtin_amdgcn_s_setprio(1);
#pragma unroll
        for (int rt=0;rt<2;++rt)
#pragma unroll
          for (int et=0;et<7;++et)
            acc[rt][et] = __builtin_amdgcn_mfma_f32_16x16x32_bf16(pf[rt], vf[et], acc[rt][et], 0,0,0);
        __builtin_amdgcn_s_setprio(0);
      }
    }
  }
  if (w < 7) {
    unsigned short* accB = accP +
      ((((size_t)(slot*2 + b)*32 + qt)*7 + w)*14)*256;
#pragma unroll
    for (int rt=0;rt<2;++rt)
#pragma unroll
      for (int et=0;et<7;++et)
#pragma unroll
        for (int r=0;r<4;++r)
          __builtin_nontemporal_store(f2bf(acc[rt][et][r]),
            &accB[(size_t)(rt*7 + et)*256 + r*64 + lane]);
  }
#pragma unroll
  for (int st=1; st<16; st<<=1)
#pragma unroll
    for (int rt=0;rt<2;++rt)
#pragma unroll
      for (int r=0;r<4;++r) lacc[rt][r] += __shfl_xor(lacc[rt][r], st);
  if (l15 == 0) {
#pragma unroll
    for (int rt=0;rt<2;++rt)
#pragma unroll
      for (int r=0;r<4;++r)
        lP[((size_t)((slot*2 + b)*8 + w) << 10) + q0 + rt*16 + g*4 + r] = lacc[rt][r];
  }
}

__global__ void __launch_bounds__(512, 2)
k_attn_all(const unsigned short* __restrict__ th,
           const unsigned short* __restrict__ ph0, const unsigned short* __restrict__ ph1,
           const unsigned short* __restrict__ ph2,
           const unsigned short* __restrict__ g80, const unsigned short* __restrict__ g81,
           const unsigned short* __restrict__ g82,
           unsigned short* __restrict__ accP, float* __restrict__ lP)
{
  __shared__ __align__(16) char smem[30464 + 2*16384];
  int bid = blockIdx.x;
  if (bid < 512)       attn_body<128,7,134,136,2048,8>(bid,      0,  th, ph0, g80, accP, lP, smem);
  else if (bid < 1024) attn_body<64,6,70,72,512,8>   (bid-512,  8,  th, ph1, g81, accP, lP, smem);
  else                 attn_body<32,5,38,40,256,4>   (bid-1024, 16, th, ph2, g82, accP, lP, smem);
}

// ---------------------------------------------------------------------------
// lG[sc][b*1024+q] = sum over chunks and waves of lP (all 3 scales)
// ---------------------------------------------------------------------------
__global__ void k_comb1_all(const float* __restrict__ lP, float* __restrict__ lG)
{
  int idx = blockIdx.x*256 + threadIdx.x;
  if (idx >= 3*2048) return;
  int sc = idx >> 11, i2 = idx & 2047;
  int b = i2 >> 10, q = i2 & 1023;
  const int NCH[3] = {8,8,4}, S0[3] = {0,8,16};
  float l = 0.f;
  for (int c=0;c<NCH[sc];++c)
#pragma unroll
    for (int w=0;w<8;++w)
      l += lP[((size_t)(((S0[sc]+c)*2 + b)*8 + w) << 10) + q];
  lG[idx] = l;
}

// ---------------------------------------------------------------------------
// Sum bf16 permuted partial accs over chunks, / lG -> yvf[sc][bq][784] (f32)
// ---------------------------------------------------------------------------
__global__ void k_comb2_all(const unsigned short* __restrict__ accP,
                            const float* __restrict__ lG, float* __restrict__ yvf)
{
  int idx = blockIdx.x*256 + threadIdx.x;
  if (idx >= 3*2048*196) return;
  int sc = idx / (2048*196);
  int rem = idx - sc*(2048*196);
  int bq = rem / 196, f4 = rem % 196;
  int b = bq >> 10, q = bq & 1023;
  int qt = q >> 5, qq = q & 31, rt = qq >> 4, g = (qq >> 2) & 3, r = qq & 3;
  int f = f4*4;
  int w = f / 112, et = (f % 112) >> 4, c = f & 15;
  const int NCH[3] = {8,8,4}, S0[3] = {0,8,16};
  float s0=0.f, s1=0.f, s2=0.f, s3=0.f;
  for (int ch=0; ch<NCH[sc]; ++ch) {
    int slot = S0[sc] + ch;
    const unsigned short* ap = accP
      + (((((size_t)(slot*2 + b)*32 + qt)*7 + w)*2 + rt)*7 + et)*256
      + r*64 + g*16 + c;
    s0 += bf2f(ap[0]); s1 += bf2f(ap[1]); s2 += bf2f(ap[2]); s3 += bf2f(ap[3]);
  }
  float inv = 1.0f / lG[sc*2048 + bq];
  float4 o; o.x=s0*inv; o.y=s1*inv; o.z=s2*inv; o.w=s3*inv;
  *(float4*)(yvf + ((size_t)sc*2048 + bq)*784 + f4*4) = o;
}

// ---------------------------------------------------------------------------
// fold (stride-4, pad 3) all 3 scales + /mask + conv1x1(w_out)+b_out + x
// ---------------------------------------------------------------------------
__global__ void k_foldfinal(const float* __restrict__ yvf, const float* __restrict__ wo,
                            const float* __restrict__ bo, const float* __restrict__ x,
                            float* __restrict__ out)
{
  __shared__ float wl[64*48];
  for (int t = threadIdx.x; t < 64*48; t += 256) wl[t] = wo[t];
  __syncthreads();
  int idx = blockIdx.x*256 + threadIdx.x;
  if (idx >= 2*128*128) return;
  int j = idx & 127; int t = idx >> 7; int i = t & 127; int b = t >> 7;

  int drs[2], qis[2], cnti=0;
  int dcs[2], qjs[2], cntj=0;
#pragma unroll
  for (int dr=0; dr<7; ++dr) {
    int tr = i + 3 - dr;
    if (tr >= 0 && (tr & 3) == 0 && (tr >> 2) < 32) { drs[cnti]=dr; qis[cnti]=tr>>2; ++cnti; }
  }
#pragma unroll
  for (int dc=0; dc<7; ++dc) {
    int tc = j + 3 - dc;
    if (tc >= 0 && (tc & 3) == 0 && (tc >> 2) < 32) { dcs[cntj]=dc; qjs[cntj]=tc>>2; ++cntj; }
  }
  float inv = 1.0f / (float)(cnti*cntj);

  float y[48];
#pragma unroll
  for (int sc=0; sc<3; ++sc) {
    const float* yb = yvf + ((size_t)sc*2048 + b*1024)*784;
    float a[16];
#pragma unroll
    for (int c=0;c<16;++c) a[c]=0.f;
    for (int u=0; u<cnti; ++u) {
      for (int v=0; v<cntj; ++v) {
        const float* src = yb + (size_t)(qis[u]*32 + qjs[v])*784 + (drs[u]*7 + dcs[v])*16;
        float4 v0 = *(const float4*)(src);
        float4 v1 = *(const float4*)(src+4);
        float4 v2 = *(const float4*)(src+8);
        float4 v3 = *(const float4*)(src+12);
        a[0]+=v0.x; a[1]+=v0.y; a[2]+=v0.z; a[3]+=v0.w;
        a[4]+=v1.x; a[5]+=v1.y; a[6]+=v1.z; a[7]+=v1.w;
        a[8]+=v2.x; a[9]+=v2.y; a[10]+=v2.z; a[11]+=v2.w;
        a[12]+=v3.x; a[13]+=v3.y; a[14]+=v3.z; a[15]+=v3.w;
      }
    }
#pragma unroll
    for (int c=0;c<16;++c) y[sc*16+c] = a[c]*inv;
  }

  const float* xb = x + (size_t)b*64*16384 + i*128 + j;
  float* ob = out + (size_t)b*64*16384 + i*128 + j;
  for (int o=0;o<64;++o) {
    float s = bo[o];
#pragma unroll
    for (int c=0;c<48;++c) s += y[c]*wl[o*48+c];
    ob[(size_t)o*16384] = s + xb[(size_t)o*16384];
  }
}

// ---------------------------------------------------------------------------
extern "C" void kernel_launch(void* const* d_in, const int* in_sizes, int n_in,
                              void* d_out, int out_size, void* d_ws, size_t ws_size,
                              hipStream_t stream)
{
  const float* x  = (const float*)d_in[0];
  const float* wt = (const float*)d_in[1];
  const float* bt = (const float*)d_in[2];
  const float* wp0= (const float*)d_in[3];
  const float* bp0= (const float*)d_in[4];
  const float* wg0= (const float*)d_in[5];
  const float* bg0= (const float*)d_in[6];
  const float* wp1= (const float*)d_in[7];
  const float* bp1= (const float*)d_in[8];
  const float* wg1= (const float*)d_in[9];
  const float* bg1= (const float*)d_in[10];
  const float* wp2= (const float*)d_in[11];
  const float* bp2= (const float*)d_in[12];
  const float* wg2= (const float*)d_in[13];
  const float* bg2= (const float*)d_in[14];
  const float* wo = (const float*)d_in[15];
  const float* bo = (const float*)d_in[16];
  float* out = (float*)d_out;
  (void)in_sizes; (void)n_in; (void)out_size; (void)ws_size;

  char* ws = (char*)d_ws;
  size_t off = 0;
  auto alloc = [&](size_t bytes)->char* { char* p = ws + off; off += (bytes + 255) & ~(size_t)255; return p; };
  unsigned short* th  = (unsigned short*)alloc(2ull*134*136*16*2);
  unsigned short* ph0 = (unsigned short*)alloc(2ull*134*136*16*2);
  unsigned short* ph1 = (unsigned short*)alloc(2ull*70*72*16*2);
  unsigned short* ph2 = (unsigned short*)alloc(2ull*38*40*16*2);
  float* gt0 = (float*)alloc(2ull*16*134*136*4);
  float* gt1 = (float*)alloc(2ull*16*70*72*4);
  float* gt2 = (float*)alloc(2ull*16*38*40*4);
  size_t zeroBytes = off;                      // th..gt2 contiguous prefix
  unsigned short* g80 = (unsigned short*)alloc(2ull*8*134*4*512*2);
  unsigned short* g81 = (unsigned short*)alloc(2ull*8*70*2*512*2);
  unsigned short* g82 = (unsigned short*)alloc(2ull*8*38*1*512*2);
  float* wT4 = (float*)alloc(1024ull*32*4);
  float* lP  = (float*)alloc(20ull*2*8*1024*4);
  float* lG  = (float*)alloc(3ull*2048*4);
  unsigned short* accP = (unsigned short*)alloc(20ull*2048*784*2);
  float* yvf = (float*)alloc(3ull*2048*784*4);

  int n16 = (int)(zeroBytes/16);
  int nzb = (n16 + 255)/256;
  k_zero_wt4<<<nzb+128,256,0,stream>>>((uint4*)ws, n16, wp2, wg2, wT4);
  k_prep_all<<<896,256,0,stream>>>(x, wt,bt, wp0,bp0,wg0,bg0, wp1,bp1,wg1,bg1,
                                   wT4, bp2,bg2, th,ph0,gt0, ph1,gt1, ph2,gt2);
  k_shift_all<<<(548864+143360+38912+255)/256,256,0,stream>>>(gt0,gt1,gt2, g80,g81,g82);
  k_attn_all<<<1280,512,0,stream>>>(th, ph0,ph1,ph2, g80,g81,g82, accP, lP);
  k_comb1_all<<<(3*2048+255)/256,256,0,stream>>>(lP, lG);
  k_comb2_all<<<(3*2048*196+255)/256,256,0,stream>>>(accP, lG, yvf);
  k_foldfinal<<<128,256,0,stream>>>(yvf, wo, bo, x, out);
}

// Round 18
// 421.038 us; speedup vs baseline: 1.3639x; 1.3639x over previous
//
#include <hip/hip_runtime.h>
#include <stdint.h>

typedef __attribute__((ext_vector_type(8))) short bf16x8;
typedef __attribute__((ext_vector_type(4))) float f32x4;
typedef __attribute__((ext_vector_type(4))) unsigned int u32x4;

#define DEV __device__ __forceinline__

DEV float bf2f(unsigned short u){ union{unsigned int i; float f;} v; v.i=((unsigned int)u)<<16; return v.f; }
DEV unsigned short f2bf(float f){ union{float f; unsigned int i;} v; v.f=f; unsigned int x=v.i;
  return (unsigned short)((x + 0x7fffu + ((x>>16)&1u)) >> 16); }

// ---------------------------------------------------------------------------
// Zero padded-border prefix (th..gt2) + transpose s=4 weights, one launch.
// ---------------------------------------------------------------------------
__global__ void k_zero_wt4(uint4* __restrict__ p, int n16,
                           const float* __restrict__ wp, const float* __restrict__ wg,
                           float* __restrict__ wT)
{
  int nzb = (n16 + 255) >> 8;
  int bid = blockIdx.x;
  if (bid < nzb) {
    int idx = bid*256 + threadIdx.x;
    if (idx < n16) p[idx] = uint4{0,0,0,0};
  } else {
    int idx = (bid - nzb)*256 + threadIdx.x;
    if (idx < 1024*32) {
      int k = idx >> 5, c = idx & 31;
      int cc = k >> 4, ksp = k & 15;
      wT[idx] = (c < 16) ? wp[(c*64+cc)*16 + ksp] : wg[((c-16)*64+cc)*16 + ksp];
    }
  }
}

// ---------------------------------------------------------------------------
// prep bodies (shared LDS buffer, routed by block range in k_prep_all).
// Weight tables staged into LDS once per block (broadcast reads after).
// ---------------------------------------------------------------------------
DEV void prep1_body(int bid, const float* __restrict__ x,
                    const float* __restrict__ wt, const float* __restrict__ bt,
                    const float* __restrict__ wp, const float* __restrict__ bp,
                    const float* __restrict__ wg, const float* __restrict__ bg,
                    unsigned short* __restrict__ th, unsigned short* __restrict__ ph,
                    float* __restrict__ gt, char* smemc)
{
  float (*red)[64][48] = (float(*)[64][48])smemc;
  float* wl = (float*)(smemc + 36864);     // wt[1024] | wp[1024] | wg[1024]
  int tid = threadIdx.x;
  for (int u = tid; u < 768; u += 256) {
    float4 v;
    if (u < 256) v = ((const float4*)wt)[u];
    else if (u < 512) v = ((const float4*)wp)[u-256];
    else v = ((const float4*)wg)[u-512];
    ((float4*)wl)[u] = v;
  }
  __syncthreads();
  int grp = tid >> 6, pixl = tid & 63;
  int pix = bid*64 + pixl;                 // [0, 32768)
  int b = pix >> 14, p = pix & 16383, i = p >> 7, j = p & 127;
  float a[48];
#pragma unroll
  for (int c=0;c<48;++c) a[c]=0.f;
  const float* xb = x + (size_t)b*64*16384 + p;
#pragma unroll
  for (int c4=0; c4<4; ++c4) {
    int cc = grp*16 + c4*4;
    float xv[4];
#pragma unroll
    for (int u=0;u<4;++u) xv[u] = xb[(size_t)(cc+u)*16384];
#pragma unroll
    for (int ic=0;ic<16;++ic) {
      float4 w0 = *(const float4*)(wl + ic*64 + cc);
      float4 w1 = *(const float4*)(wl + 1024 + ic*64 + cc);
      float4 w2 = *(const float4*)(wl + 2048 + ic*64 + cc);
      a[ic]    += xv[0]*w0.x + xv[1]*w0.y + xv[2]*w0.z + xv[3]*w0.w;
      a[16+ic] += xv[0]*w1.x + xv[1]*w1.y + xv[2]*w1.z + xv[3]*w1.w;
      a[32+ic] += xv[0]*w2.x + xv[1]*w2.y + xv[2]*w2.z + xv[3]*w2.w;
    }
  }
  if (grp) {
#pragma unroll
    for (int c=0;c<48;++c) red[grp-1][pixl][c] = a[c];
  }
  __syncthreads();
  if (grp == 0) {
#pragma unroll
    for (int c=0;c<48;++c) a[c] += red[0][pixl][c] + red[1][pixl][c] + red[2][pixl][c];
    const float TEMPC = 14.426950408889634f;
    unsigned short o[16];
#pragma unroll
    for (int ic=0;ic<16;++ic) o[ic] = f2bf((a[ic]+bt[ic])*TEMPC);
    uint4* d0 = (uint4*)(th + ((size_t)(b*134 + i+3)*136 + (j+3))*16);
    d0[0]=*(uint4*)&o[0]; d0[1]=*(uint4*)&o[8];
#pragma unroll
    for (int ic=0;ic<16;++ic) o[ic] = f2bf(a[16+ic]+bp[ic]);
    uint4* d1 = (uint4*)(ph + ((size_t)(b*134 + i+3)*136 + (j+3))*16);
    d1[0]=*(uint4*)&o[0]; d1[1]=*(uint4*)&o[8];
#pragma unroll
    for (int ic=0;ic<16;++ic)
      gt[(((size_t)b*16+ic)*134 + i+3)*136 + (j+3)] = a[32+ic]+bg[ic];
  }
}

DEV void conv2_body(int bid, const float* __restrict__ x,
                    const float* __restrict__ wp, const float* __restrict__ bp,
                    const float* __restrict__ wg, const float* __restrict__ bg,
                    unsigned short* __restrict__ phi, float* __restrict__ gt, char* smemc)
{
  float (*red)[64][32] = (float(*)[64][32])smemc;
  float* wl = (float*)(smemc + 24576);     // wp[4096] | wg[4096]
  int tid = threadIdx.x;
  for (int u = tid; u < 2048; u += 256) {
    float4 v = (u < 1024) ? ((const float4*)wp)[u] : ((const float4*)wg)[u-1024];
    ((float4*)wl)[u] = v;
  }
  __syncthreads();
  int grp = tid >> 6, pixl = tid & 63;
  int pix = bid*64 + pixl;                 // [0, 8192)
  int b = pix >> 12, p = pix & 4095, i = p >> 6, j = p & 63;
  float a[32];
#pragma unroll
  for (int c=0;c<32;++c) a[c]=0.f;
  const float* xb = x + (size_t)b*64*16384 + (i*2)*128 + j*2;
#pragma unroll
  for (int c0=0; c0<16; ++c0) {
    int cc = grp*16 + c0;
    const float* xp = xb + (size_t)cc*16384;
    float xv[4];
    xv[0]=xp[0]; xv[1]=xp[1]; xv[2]=xp[128]; xv[3]=xp[129];
#pragma unroll
    for (int ic=0;ic<16;++ic) {
      float4 w0 = *(const float4*)(wl + (ic*64+cc)*4);
      float4 w1 = *(const float4*)(wl + 4096 + (ic*64+cc)*4);
      a[ic]    += xv[0]*w0.x + xv[1]*w0.y + xv[2]*w0.z + xv[3]*w0.w;
      a[16+ic] += xv[0]*w1.x + xv[1]*w1.y + xv[2]*w1.z + xv[3]*w1.w;
    }
  }
  if (grp) {
#pragma unroll
    for (int c=0;c<32;++c) red[grp-1][pixl][c] = a[c];
  }
  __syncthreads();
  if (grp == 0) {
#pragma unroll
    for (int c=0;c<32;++c) a[c] += red[0][pixl][c] + red[1][pixl][c] + red[2][pixl][c];
    unsigned short o[16];
#pragma unroll
    for (int ic=0;ic<16;++ic) o[ic] = f2bf(a[ic]+bp[ic]);
    uint4* d1 = (uint4*)(phi + ((size_t)(b*70 + i+3)*72 + (j+3))*16);
    d1[0]=*(uint4*)&o[0]; d1[1]=*(uint4*)&o[8];
#pragma unroll
    for (int ic=0;ic<16;++ic)
      gt[(((size_t)b*16+ic)*70 + i+3)*72 + (j+3)] = a[16+ic]+bg[ic];
  }
}

DEV void conv4_body(int bid, const float* __restrict__ x, const float* __restrict__ wT,
                    const float* __restrict__ bp, const float* __restrict__ bg,
                    unsigned short* __restrict__ phi, float* __restrict__ gt, char* smemc)
{
  float (*xs)[1028] = (float(*)[1028])smemc;
  int tid = threadIdx.x;
  int pix0 = bid*8;                        // [0,2048) step 8
  for (int idx = tid; idx < 8*1024; idx += 256) {
    int pl = idx >> 10, e = idx & 1023;
    int pix = pix0 + pl; int b = pix >> 10, p = pix & 1023, i = p >> 5, j = p & 31;
    int cc = e >> 4, a_ = (e >> 2) & 3, bb = e & 3;
    xs[pl][e] = x[(((size_t)b*64+cc)*128 + i*4+a_)*128 + j*4+bb];
  }
  __syncthreads();
  int pp = tid >> 5, icp = tid & 31;
  int pix = pix0 + pp; int b = pix >> 10, p = pix & 1023, i = p >> 5, j = p & 31;
  float acc = 0.f;
#pragma unroll 8
  for (int k4=0; k4<256; ++k4) {
    float4 xv = *(const float4*)(&xs[pp][k4*4]);
    acc += xv.x*wT[(k4*4  )*32+icp] + xv.y*wT[(k4*4+1)*32+icp]
         + xv.z*wT[(k4*4+2)*32+icp] + xv.w*wT[(k4*4+3)*32+icp];
  }
  int ic = icp & 15;
  if (icp < 16)
    phi[(((size_t)(b*38 + i+3)*40) + (j+3))*16 + ic] = f2bf(acc + bp[ic]);
  else
    gt[(((size_t)b*16+ic)*38 + i+3)*40 + (j+3)] = acc + bg[ic];
}

__global__ void k_prep_all(const float* __restrict__ x,
                           const float* __restrict__ wt, const float* __restrict__ bt,
                           const float* __restrict__ wp0, const float* __restrict__ bp0,
                           const float* __restrict__ wg0, const float* __restrict__ bg0,
                           const float* __restrict__ wp1, const float* __restrict__ bp1,
                           const float* __restrict__ wg1, const float* __restrict__ bg1,
                           const float* __restrict__ wT4, const float* __restrict__ bp2,
                           const float* __restrict__ bg2,
                           unsigned short* __restrict__ th, unsigned short* __restrict__ ph0,
                           float* __restrict__ gt0,
                           unsigned short* __restrict__ ph1, float* __restrict__ gt1,
                           unsigned short* __restrict__ ph2, float* __restrict__ gt2)
{
  __shared__ __align__(16) char smem[57344];
  int bid = blockIdx.x;
  if (bid < 512)      prep1_body(bid, x, wt,bt, wp0,bp0, wg0,bg0, th, ph0, gt0, smem);
  else if (bid < 640) conv2_body(bid-512, x, wp1,bp1, wg1,bg1, ph1, gt1, smem);
  else                conv4_body(bid-640, x, wT4, bp2, bg2, ph2, gt2, smem);
}

// ---------------------------------------------------------------------------
// V tile buffer: g8b[b][sh][y][xb][c][32] bf16 (1KB tile per (sh,y,xb)).
// ---------------------------------------------------------------------------
template<int HP, int WX, int HS>
DEV void shift_body(int idx, const float* __restrict__ gt, unsigned short* __restrict__ g8b)
{
  const int XB = HS/32;
  int xkg = idx & 3;
  int c = (idx >> 2) & 15;
  int t = idx >> 6;
  int xb = t % XB; t /= XB;
  int y = t % HP; t /= HP;
  int sh = t & 7; int b = t >> 3;
  const float* src = gt + (((size_t)b*16+c)*HP + y)*WX + xb*32 + xkg*8 + sh;
  unsigned short o[8];
#pragma unroll
  for (int j=0;j<8;++j) o[j] = f2bf(src[j]);
  unsigned short* dst = g8b + ((((size_t)(b*8+sh)*HP + y)*XB + xb)*16 + c)*32 + xkg*8;
  *(uint4*)dst = *(uint4*)&o[0];
}

__global__ void k_shift_all(const float* __restrict__ gt0, const float* __restrict__ gt1,
                            const float* __restrict__ gt2,
                            unsigned short* __restrict__ g80, unsigned short* __restrict__ g81,
                            unsigned short* __restrict__ g82)
{
  const int T0 = 2*8*134*4*16*4;           // 548864
  const int T1 = 2*8*70*2*16*4;            // 143360
  const int T2 = 2*8*38*1*16*4;            // 38912
  int idx = blockIdx.x*256 + threadIdx.x;
  if (idx < T0) { shift_body<134,136,128>(idx, gt0, g80); return; }
  idx -= T0;
  if (idx < T1) { shift_body<70,72,64>(idx, gt1, g81); return; }
  idx -= T1;
  if (idx < T2) { shift_body<38,40,32>(idx, gt2, g82); }
}

// ---------------------------------------------------------------------------
// Flash attention body (round-16 structure, unchanged): fixed shift
// P=exp2(min(sc-64,120)), Q-tile 32, 8 waves, 256 keys/iter, P double-buffer
// + one barrier/iter; theta in swizzled LDS; phi global; V nontemporal.
// accP bf16 nontemporal, permuted coalesced layout (128B stores).
// ---------------------------------------------------------------------------
template<int HS, int LG, int HP, int WX, int CK, int NCH>
DEV void attn_body(int bid, int slot0,
                   const unsigned short* __restrict__ th,
                   const unsigned short* __restrict__ phi,
                   const unsigned short* __restrict__ g8b,
                   unsigned short* __restrict__ accP, float* __restrict__ lP, char* smem)
{
  const int PO = 30464;
  int tid = threadIdx.x;
  int w = tid >> 6, lane = tid & 63, l15 = lane & 15, g = lane >> 4;
  int chunk, b, qt;
  if (NCH == 8) { chunk = bid & 7; b = (bid >> 3) & 1; qt = bid >> 4; }
  else          { chunk = bid & 3; b = (bid >> 2) & 1; qt = bid >> 3; }
  int q0 = qt * 32;
  int slot = slot0 + chunk;

  const char* thB  = (const char*)th  + (size_t)b*134*136*32;
  const char* phiB = (const char*)phi + (size_t)b*HP*WX*32;

  // ---- stage theta window (rows 4qt+2 .. 4qt+8) into swizzled LDS ----
  for (int u = tid; u < 7*136*2; u += 512) {
    int half = u & 1; int cu = (u >> 1) % 136; int r = (u >> 1) / 136;
    uint4 v = *(const uint4*)(thB + (((4*qt+2+r)*136 + cu)*32 + half*16));
    int la = (((r*136 + cu)*32) + half*16) ^ (((cu >> 2) & 7) << 4);
    *(uint4*)(smem + la) = v;
  }
  __syncthreads();

  f32x4 acc[2][7];
#pragma unroll
  for (int rt=0;rt<2;++rt)
#pragma unroll
    for (int et=0;et<7;++et) acc[rt][et] = f32x4{0.f,0.f,0.f,0.f};
  float lacc[2][4];
#pragma unroll
  for (int rt=0;rt<2;++rt)
#pragma unroll
    for (int r=0;r<4;++r) lacc[rt][r] = 0.f;

  const int XBv = HS/32;
  const char* g8B  = (const char*)g8b + (size_t)b*8*HP*XBv*1024;
  const int EPL = HP*XBv*1024;                 // bytes per shift-plane
  int laneVb = l15*64 + g*16;                  // within 1KB tile
  int xrP = (l15 & 7) << 4;                    // P-lds read swizzle
  int colb = 4*l15 + 2;                        // theta col base (a0); a1 = +64
  int hb = (g & 1) << 4;
  const bf16x8 ZV = {0,0,0,0,0,0,0,0};
  const int ITERS = CK/256;
  const float SHIFT = 64.0f, CLAMP = 120.0f;

#pragma unroll 1
  for (int it = 0; it < ITERS; ++it) {
    int k0 = chunk*CK + it*256;
    int po = PO + ((it & 1) << 14);            // P double-buffer
    // ---------------- QK ----------------
    f32x4 sc[2][2];
#pragma unroll
    for (int rt=0;rt<2;++rt){ sc[rt][0]=f32x4{0.f,0.f,0.f,0.f}; sc[rt][1]=f32x4{0.f,0.f,0.f,0.f}; }
    int kr_w = (k0 + w*32) >> LG;
    int kc_w = (w*32) & (HS-1);
    int base0 = (kr_w*WX + kc_w + l15)*32 + hb;
    int base1 = base0 + 512;
#pragma unroll
    for (int ks=0; ks<25; ++ks) {
      int p0 = 2*ks;
      int p1 = (2*ks+1 > 48) ? 48 : 2*ks+1;
      int dr0 = p0/7, dc0 = p0%7;
      int dr1 = p1/7, dc1 = p1%7;
      int c0 = colb + dc0, c1 = colb + dc1;
      int la0 = ((dr0*136 + c0)*32 + hb) ^ (((c0 >> 2) & 7) << 4);
      int la1 = ((dr1*136 + c1)*32 + hb) ^ (((c1 >> 2) & 7) << 4);
      int laA = (g & 2) ? la1 : la0;
      int KB0 = (dr0*WX + dc0)*32;
      int KB1 = (dr1*WX + dc1)*32;
      int selB = (g & 2) ? KB1 : KB0;
      bf16x8 a0 = *(const bf16x8*)(smem + laA);
      bf16x8 a1 = *(const bf16x8*)(smem + laA + 2048);   // +64 cols, same swizzle
      if (ks == 24) {
        bool z = (g & 2) != 0;
        a0 = z ? ZV : a0; a1 = z ? ZV : a1;
      }
      bf16x8 b0 = *(const bf16x8*)(phiB + base0 + selB);
      bf16x8 b1 = *(const bf16x8*)(phiB + base1 + selB);
      sc[0][0] = __builtin_amdgcn_mfma_f32_16x16x32_bf16(a0, b0, sc[0][0], 0,0,0);
      sc[0][1] = __builtin_amdgcn_mfma_f32_16x16x32_bf16(a0, b1, sc[0][1], 0,0,0);
      sc[1][0] = __builtin_amdgcn_mfma_f32_16x16x32_bf16(a1, b0, sc[1][0], 0,0,0);
      sc[1][1] = __builtin_amdgcn_mfma_f32_16x16x32_bf16(a1, b1, sc[1][1], 0,0,0);
    }
    // ---------------- P = exp2(min(S-64,120)), accumulate l, write P_lds ----------------
#pragma unroll
    for (int rt=0;rt<2;++rt) {
#pragma unroll
      for (int r=0;r<4;++r) {
        float pa = __builtin_amdgcn_exp2f(fminf(sc[rt][0][r] - SHIFT, CLAMP));
        float pb = __builtin_amdgcn_exp2f(fminf(sc[rt][1][r] - SHIFT, CLAMP));
        lacc[rt][r] += pa + pb;
        int q_ = rt*16 + g*4 + r;
        int offa = q_*512 + (w*32 + l15)*2;      offa ^= (q_&7)<<4;
        int offb = q_*512 + (w*32 + 16 + l15)*2; offb ^= (q_&7)<<4;
        *(unsigned short*)(smem + po + offa) = f2bf(pa);
        *(unsigned short*)(smem + po + offb) = f2bf(pb);
      }
    }
    __syncthreads();       // single barrier: P[cur] ready; PV[prev] readers done
    // ---------------- PV (overlaps next-iter QK loads) ----------------
    if (w < 7) {
#pragma unroll
      for (int ks2=0; ks2<8; ++ks2) {
        int kk = k0 + ks2*32;
        int krv = kk >> LG;
        int kcb = kk & (HS-1);
        bf16x8 pf[2];
#pragma unroll
        for (int rt=0;rt<2;++rt) {
          int off = (rt*16 + l15)*512 + ks2*64 + g*16;
          off ^= xrP;
          pf[rt] = *(const bf16x8*)(smem + po + off);
        }
        int vb = ((krv + w)*XBv + (kcb >> 5))*1024 + laneVb;
        bf16x8 vf[7];
#pragma unroll
        for (int et=0;et<7;++et) {
          u32x4 t0 = __builtin_nontemporal_load((const u32x4*)(g8B + vb + et*EPL));
          vf[et] = *(bf16x8*)&t0;
        }
        __builtin_amdgcn_s_setprio(1);
#pragma unroll
        for (int rt=0;rt<2;++rt)
#pragma unroll
          for (int et=0;et<7;++et)
            acc[rt][et] = __builtin_amdgcn_mfma_f32_16x16x32_bf16(pf[rt], vf[et], acc[rt][et], 0,0,0);
        __builtin_amdgcn_s_setprio(0);
      }
    }
  }
  if (w < 7) {
    unsigned short* accB = accP +
      ((((size_t)(slot*2 + b)*32 + qt)*7 + w)*14)*256;
#pragma unroll
    for (int rt=0;rt<2;++rt)
#pragma unroll
      for (int et=0;et<7;++et)
#pragma unroll
        for (int r=0;r<4;++r)
          __builtin_nontemporal_store(f2bf(acc[rt][et][r]),
            &accB[(size_t)(rt*7 + et)*256 + r*64 + lane]);
  }
#pragma unroll
  for (int st=1; st<16; st<<=1)
#pragma unroll
    for (int rt=0;rt<2;++rt)
#pragma unroll
      for (int r=0;r<4;++r) lacc[rt][r] += __shfl_xor(lacc[rt][r], st);
  if (l15 == 0) {
#pragma unroll
    for (int rt=0;rt<2;++rt)
#pragma unroll
      for (int r=0;r<4;++r)
        lP[((size_t)((slot*2 + b)*8 + w) << 10) + q0 + rt*16 + g*4 + r] = lacc[rt][r];
  }
}

__global__ void __launch_bounds__(512, 2)
k_attn_all(const unsigned short* __restrict__ th,
           const unsigned short* __restrict__ ph0, const unsigned short* __restrict__ ph1,
           const unsigned short* __restrict__ ph2,
           const unsigned short* __restrict__ g80, const unsigned short* __restrict__ g81,
           const unsigned short* __restrict__ g82,
           unsigned short* __restrict__ accP, float* __restrict__ lP)
{
  __shared__ __align__(16) char smem[30464 + 2*16384];
  int bid = blockIdx.x;
  if (bid < 512)       attn_body<128,7,134,136,2048,8>(bid,      0,  th, ph0, g80, accP, lP, smem);
  else if (bid < 1024) attn_body<64,6,70,72,512,8>   (bid-512,  8,  th, ph1, g81, accP, lP, smem);
  else                 attn_body<32,5,38,40,256,4>   (bid-1024, 16, th, ph2, g82, accP, lP, smem);
}

// ---------------------------------------------------------------------------
// lG[sc][b*1024+q] = sum over chunks and waves of lP (all 3 scales)
// ---------------------------------------------------------------------------
__global__ void k_comb1_all(const float* __restrict__ lP, float* __restrict__ lG)
{
  int idx = blockIdx.x*256 + threadIdx.x;
  if (idx >= 3*2048) return;
  int sc = idx >> 11, i2 = idx & 2047;
  int b = i2 >> 10, q = i2 & 1023;
  const int NCH[3] = {8,8,4}, S0[3] = {0,8,16};
  float l = 0.f;
  for (int c=0;c<NCH[sc];++c)
#pragma unroll
    for (int w=0;w<8;++w)
      l += lP[((size_t)(((S0[sc]+c)*2 + b)*8 + w) << 10) + q];
  lG[idx] = l;
}

// ---------------------------------------------------------------------------
// Coalesced comb2: iterate accP in native permuted linear order. Thread sums
// 8 contiguous bf16 (16B loads, nt) across chunks, divides by lG (8 elems
// share one query), writes 32B contiguous to permuted yvfP (same layout).
// e = ((((b*32+qt)*7+w)*2+rt)*7+et)*256 + r*64+g*16+c ; slot stride 1605632.
// ---------------------------------------------------------------------------
__global__ void k_comb2_all(const unsigned short* __restrict__ accP,
                            const float* __restrict__ lG, float* __restrict__ yvfP)
{
  int t8 = blockIdx.x*256 + threadIdx.x;
  if (t8 >= 3*200704) return;              // 2048*784/8 per scale
  int sc = t8 / 200704;
  int rem = t8 - sc*200704;
  int e = rem*8;
  int low = e & 255;
  int r = low >> 6, g = (low >> 4) & 3;
  int tile = e >> 8;
  int et = tile % 7; int tt = tile / 7;
  int rt = tt & 1; tt >>= 1;
  int w = tt % 7; tt /= 7;
  int qt = tt & 31; int b = tt >> 5;
  int bq = (b << 10) + qt*32 + rt*16 + g*4 + r;
  const int NCH[3] = {8,8,4}, S0[3] = {0,8,16};
  float s[8];
#pragma unroll
  for (int u=0;u<8;++u) s[u]=0.f;
  for (int ch=0; ch<NCH[sc]; ++ch) {
    const unsigned short* ap = accP + (size_t)(S0[sc]+ch)*1605632 + e;
    u32x4 v = __builtin_nontemporal_load((const u32x4*)ap);
    const unsigned short* pv = (const unsigned short*)&v;
#pragma unroll
    for (int u=0;u<8;++u) s[u] += bf2f(pv[u]);
  }
  float inv = 1.0f / lG[sc*2048 + bq];
  float* dst = yvfP + (size_t)sc*1605632 + e;
  float4 o0, o1;
  o0.x=s[0]*inv; o0.y=s[1]*inv; o0.z=s[2]*inv; o0.w=s[3]*inv;
  o1.x=s[4]*inv; o1.y=s[5]*inv; o1.z=s[6]*inv; o1.w=s[7]*inv;
  *(float4*)dst = o0; *(float4*)(dst+4) = o1;
}

// ---------------------------------------------------------------------------
// fold (stride-4, pad 3) all 3 scales from permuted yvfP + /mask +
// conv1x1(w_out)+b_out + x
// ---------------------------------------------------------------------------
__global__ void k_foldfinal(const float* __restrict__ yvfP, const float* __restrict__ wo,
                            const float* __restrict__ bo, const float* __restrict__ x,
                            float* __restrict__ out)
{
  __shared__ float wl[64*48];
  for (int t = threadIdx.x; t < 64*48; t += 256) wl[t] = wo[t];
  __syncthreads();
  int idx = blockIdx.x*256 + threadIdx.x;
  if (idx >= 2*128*128) return;
  int j = idx & 127; int t = idx >> 7; int i = t & 127; int b = t >> 7;

  int drs[2], qis[2], cnti=0;
  int dcs[2], qjs[2], cntj=0;
#pragma unroll
  for (int dr=0; dr<7; ++dr) {
    int tr = i + 3 - dr;
    if (tr >= 0 && (tr & 3) == 0 && (tr >> 2) < 32) { drs[cnti]=dr; qis[cnti]=tr>>2; ++cnti; }
  }
#pragma unroll
  for (int dc=0; dc<7; ++dc) {
    int tc = j + 3 - dc;
    if (tc >= 0 && (tc & 3) == 0 && (tc >> 2) < 32) { dcs[cntj]=dc; qjs[cntj]=tc>>2; ++cntj; }
  }
  float inv = 1.0f / (float)(cnti*cntj);

  float y[48];
#pragma unroll
  for (int sc=0; sc<3; ++sc) {
    const float* yb = yvfP + (size_t)sc*1605632;
    float a[16];
#pragma unroll
    for (int c=0;c<16;++c) a[c]=0.f;
    for (int u=0; u<cnti; ++u) {
      for (int v=0; v<cntj; ++v) {
        int q = qis[u]*32 + qjs[v];
        int qt = q >> 5, rt = (q >> 4) & 1, gg = (q >> 2) & 3, rr = q & 3;
        int off = ((((b*32 + qt)*7 + drs[u])*2 + rt)*7 + dcs[v])*256 + rr*64 + gg*16;
        const float* src = yb + off;
        float4 v0 = *(const float4*)(src);
        float4 v1 = *(const float4*)(src+4);
        float4 v2 = *(const float4*)(src+8);
        float4 v3 = *(const float4*)(src+12);
        a[0]+=v0.x; a[1]+=v0.y; a[2]+=v0.z; a[3]+=v0.w;
        a[4]+=v1.x; a[5]+=v1.y; a[6]+=v1.z; a[7]+=v1.w;
        a[8]+=v2.x; a[9]+=v2.y; a[10]+=v2.z; a[11]+=v2.w;
        a[12]+=v3.x; a[13]+=v3.y; a[14]+=v3.z; a[15]+=v3.w;
      }
    }
#pragma unroll
    for (int c=0;c<16;++c) y[sc*16+c] = a[c]*inv;
  }

  const float* xb = x + (size_t)b*64*16384 + i*128 + j;
  float* ob = out + (size_t)b*64*16384 + i*128 + j;
  for (int o=0;o<64;++o) {
    float s = bo[o];
#pragma unroll
    for (int c=0;c<48;++c) s += y[c]*wl[o*48+c];
    ob[(size_t)o*16384] = s + xb[(size_t)o*16384];
  }
}

// ---------------------------------------------------------------------------
extern "C" void kernel_launch(void* const* d_in, const int* in_sizes, int n_in,
                              void* d_out, int out_size, void* d_ws, size_t ws_size,
                              hipStream_t stream)
{
  const float* x  = (const float*)d_in[0];
  const float* wt = (const float*)d_in[1];
  const float* bt = (const float*)d_in[2];
  const float* wp0= (const float*)d_in[3];
  const float* bp0= (const float*)d_in[4];
  const float* wg0= (const float*)d_in[5];
  const float* bg0= (const float*)d_in[6];
  const float* wp1= (const float*)d_in[7];
  const float* bp1= (const float*)d_in[8];
  const float* wg1= (const float*)d_in[9];
  const float* bg1= (const float*)d_in[10];
  const float* wp2= (const float*)d_in[11];
  const float* bp2= (const float*)d_in[12];
  const float* wg2= (const float*)d_in[13];
  const float* bg2= (const float*)d_in[14];
  const float* wo = (const float*)d_in[15];
  const float* bo = (const float*)d_in[16];
  float* out = (float*)d_out;
  (void)in_sizes; (void)n_in; (void)out_size; (void)ws_size;

  char* ws = (char*)d_ws;
  size_t off = 0;
  auto alloc = [&](size_t bytes)->char* { char* p = ws + off; off += (bytes + 255) & ~(size_t)255; return p; };
  unsigned short* th  = (unsigned short*)alloc(2ull*134*136*16*2);
  unsigned short* ph0 = (unsigned short*)alloc(2ull*134*136*16*2);
  unsigned short* ph1 = (unsigned short*)alloc(2ull*70*72*16*2);
  unsigned short* ph2 = (unsigned short*)alloc(2ull*38*40*16*2);
  float* gt0 = (float*)alloc(2ull*16*134*136*4);
  float* gt1 = (float*)alloc(2ull*16*70*72*4);
  float* gt2 = (float*)alloc(2ull*16*38*40*4);
  size_t zeroBytes = off;                      // th..gt2 contiguous prefix
  unsigned short* g80 = (unsigned short*)alloc(2ull*8*134*4*512*2);
  unsigned short* g81 = (unsigned short*)alloc(2ull*8*70*2*512*2);
  unsigned short* g82 = (unsigned short*)alloc(2ull*8*38*1*512*2);
  float* wT4 = (float*)alloc(1024ull*32*4);
  float* lP  = (float*)alloc(20ull*2*8*1024*4);
  float* lG  = (float*)alloc(3ull*2048*4);
  unsigned short* accP = (unsigned short*)alloc(20ull*2048*784*2);
  float* yvfP = (float*)alloc(3ull*2048*784*4);

  int n16 = (int)(zeroBytes/16);
  int nzb = (n16 + 255)/256;
  k_zero_wt4<<<nzb+128,256,0,stream>>>((uint4*)ws, n16, wp2, wg2, wT4);
  k_prep_all<<<896,256,0,stream>>>(x, wt,bt, wp0,bp0,wg0,bg0, wp1,bp1,wg1,bg1,
                                   wT4, bp2,bg2, th,ph0,gt0, ph1,gt1, ph2,gt2);
  k_shift_all<<<(548864+143360+38912+255)/256,256,0,stream>>>(gt0,gt1,gt2, g80,g81,g82);
  k_attn_all<<<1280,512,0,stream>>>(th, ph0,ph1,ph2, g80,g81,g82, accP, lP);
  k_comb1_all<<<(3*2048+255)/256,256,0,stream>>>(lP, lG);
  k_comb2_all<<<(3*200704+255)/256,256,0,stream>>>(accP, lG, yvfP);
  k_foldfinal<<<128,256,0,stream>>>(yvfP, wo, bo, x, out);
}

// Round 20
// 413.563 us; speedup vs baseline: 1.3885x; 1.0181x over previous
//
#include <hip/hip_runtime.h>
#include <stdint.h>

typedef __attribute__((ext_vector_type(8))) short bf16x8;
typedef __attribute__((ext_vector_type(4))) float f32x4;
typedef __attribute__((ext_vector_type(4))) unsigned int u32x4;

#define DEV __device__ __forceinline__

DEV float bf2f(unsigned short u){ union{unsigned int i; float f;} v; v.i=((unsigned int)u)<<16; return v.f; }
DEV unsigned short f2bf(float f){ union{float f; unsigned int i;} v; v.f=f; unsigned int x=v.i;
  return (unsigned short)((x + 0x7fffu + ((x>>16)&1u)) >> 16); }

// ---------------------------------------------------------------------------
// Zero the padded-border prefix (th..gt2). MUST run before k_prep_all
// (separate launch: no inter-block ordering exists within one grid).
// ---------------------------------------------------------------------------
__global__ void k_zero(uint4* __restrict__ p, int n16)
{
  int idx = blockIdx.x*256 + threadIdx.x;
  if (idx < n16) p[idx] = uint4{0,0,0,0};
}

// ---------------------------------------------------------------------------
// prep bodies (shared LDS buffer, routed by block range in k_prep_all).
// ---------------------------------------------------------------------------
DEV void prep1_body(int bid, const float* __restrict__ x,
                    const float* __restrict__ wt, const float* __restrict__ bt,
                    const float* __restrict__ wp, const float* __restrict__ bp,
                    const float* __restrict__ wg, const float* __restrict__ bg,
                    unsigned short* __restrict__ th, unsigned short* __restrict__ ph,
                    float* __restrict__ gt, char* smemc)
{
  float (*red)[64][48] = (float(*)[64][48])smemc;
  float* wl = (float*)(smemc + 36864);     // wt[1024] | wp[1024] | wg[1024]
  int tid = threadIdx.x;
  for (int u = tid; u < 768; u += 256) {
    float4 v;
    if (u < 256) v = ((const float4*)wt)[u];
    else if (u < 512) v = ((const float4*)wp)[u-256];
    else v = ((const float4*)wg)[u-512];
    ((float4*)wl)[u] = v;
  }
  __syncthreads();
  int grp = tid >> 6, pixl = tid & 63;
  int pix = bid*64 + pixl;                 // [0, 32768)
  int b = pix >> 14, p = pix & 16383, i = p >> 7, j = p & 127;
  float a[48];
#pragma unroll
  for (int c=0;c<48;++c) a[c]=0.f;
  const float* xb = x + (size_t)b*64*16384 + p;
#pragma unroll
  for (int c4=0; c4<4; ++c4) {
    int cc = grp*16 + c4*4;
    float xv[4];
#pragma unroll
    for (int u=0;u<4;++u) xv[u] = xb[(size_t)(cc+u)*16384];
#pragma unroll
    for (int ic=0;ic<16;++ic) {
      float4 w0 = *(const float4*)(wl + ic*64 + cc);
      float4 w1 = *(const float4*)(wl + 1024 + ic*64 + cc);
      float4 w2 = *(const float4*)(wl + 2048 + ic*64 + cc);
      a[ic]    += xv[0]*w0.x + xv[1]*w0.y + xv[2]*w0.z + xv[3]*w0.w;
      a[16+ic] += xv[0]*w1.x + xv[1]*w1.y + xv[2]*w1.z + xv[3]*w1.w;
      a[32+ic] += xv[0]*w2.x + xv[1]*w2.y + xv[2]*w2.z + xv[3]*w2.w;
    }
  }
  if (grp) {
#pragma unroll
    for (int c=0;c<48;++c) red[grp-1][pixl][c] = a[c];
  }
  __syncthreads();
  if (grp == 0) {
#pragma unroll
    for (int c=0;c<48;++c) a[c] += red[0][pixl][c] + red[1][pixl][c] + red[2][pixl][c];
    const float TEMPC = 14.426950408889634f;
    unsigned short o[16];
#pragma unroll
    for (int ic=0;ic<16;++ic) o[ic] = f2bf((a[ic]+bt[ic])*TEMPC);
    uint4* d0 = (uint4*)(th + ((size_t)(b*134 + i+3)*136 + (j+3))*16);
    d0[0]=*(uint4*)&o[0]; d0[1]=*(uint4*)&o[8];
#pragma unroll
    for (int ic=0;ic<16;++ic) o[ic] = f2bf(a[16+ic]+bp[ic]);
    uint4* d1 = (uint4*)(ph + ((size_t)(b*134 + i+3)*136 + (j+3))*16);
    d1[0]=*(uint4*)&o[0]; d1[1]=*(uint4*)&o[8];
#pragma unroll
    for (int ic=0;ic<16;++ic)
      gt[(((size_t)b*16+ic)*134 + i+3)*136 + (j+3)] = a[32+ic]+bg[ic];
  }
}

DEV void conv2_body(int bid, const float* __restrict__ x,
                    const float* __restrict__ wp, const float* __restrict__ bp,
                    const float* __restrict__ wg, const float* __restrict__ bg,
                    unsigned short* __restrict__ phi, float* __restrict__ gt, char* smemc)
{
  float (*red)[64][32] = (float(*)[64][32])smemc;
  float* wl = (float*)(smemc + 24576);     // wp[4096] | wg[4096]
  int tid = threadIdx.x;
  for (int u = tid; u < 2048; u += 256) {
    float4 v = (u < 1024) ? ((const float4*)wp)[u] : ((const float4*)wg)[u-1024];
    ((float4*)wl)[u] = v;
  }
  __syncthreads();
  int grp = tid >> 6, pixl = tid & 63;
  int pix = bid*64 + pixl;                 // [0, 8192)
  int b = pix >> 12, p = pix & 4095, i = p >> 6, j = p & 63;
  float a[32];
#pragma unroll
  for (int c=0;c<32;++c) a[c]=0.f;
  const float* xb = x + (size_t)b*64*16384 + (i*2)*128 + j*2;
#pragma unroll
  for (int c0=0; c0<16; ++c0) {
    int cc = grp*16 + c0;
    const float* xp = xb + (size_t)cc*16384;
    float xv[4];
    xv[0]=xp[0]; xv[1]=xp[1]; xv[2]=xp[128]; xv[3]=xp[129];
#pragma unroll
    for (int ic=0;ic<16;++ic) {
      float4 w0 = *(const float4*)(wl + (ic*64+cc)*4);
      float4 w1 = *(const float4*)(wl + 4096 + (ic*64+cc)*4);
      a[ic]    += xv[0]*w0.x + xv[1]*w0.y + xv[2]*w0.z + xv[3]*w0.w;
      a[16+ic] += xv[0]*w1.x + xv[1]*w1.y + xv[2]*w1.z + xv[3]*w1.w;
    }
  }
  if (grp) {
#pragma unroll
    for (int c=0;c<32;++c) red[grp-1][pixl][c] = a[c];
  }
  __syncthreads();
  if (grp == 0) {
#pragma unroll
    for (int c=0;c<32;++c) a[c] += red[0][pixl][c] + red[1][pixl][c] + red[2][pixl][c];
    unsigned short o[16];
#pragma unroll
    for (int ic=0;ic<16;++ic) o[ic] = f2bf(a[ic]+bp[ic]);
    uint4* d1 = (uint4*)(phi + ((size_t)(b*70 + i+3)*72 + (j+3))*16);
    d1[0]=*(uint4*)&o[0]; d1[1]=*(uint4*)&o[8];
#pragma unroll
    for (int ic=0;ic<16;++ic)
      gt[(((size_t)b*16+ic)*70 + i+3)*72 + (j+3)] = a[16+ic]+bg[ic];
  }
}

// conv4 with RAW weight reads: thread (icp) reads contiguous w[ic*1024 + k]
// (k = cc*16 + a*4 + bb matches xs element order) -> float4 loads, L2-resident.
DEV void conv4_body(int bid, const float* __restrict__ x,
                    const float* __restrict__ wp, const float* __restrict__ wg,
                    const float* __restrict__ bp, const float* __restrict__ bg,
                    unsigned short* __restrict__ phi, float* __restrict__ gt, char* smemc)
{
  float (*xs)[1028] = (float(*)[1028])smemc;
  int tid = threadIdx.x;
  int pix0 = bid*8;                        // [0,2048) step 8
  for (int idx = tid; idx < 8*1024; idx += 256) {
    int pl = idx >> 10, e = idx & 1023;
    int pix = pix0 + pl; int b = pix >> 10, p = pix & 1023, i = p >> 5, j = p & 31;
    int cc = e >> 4, a_ = (e >> 2) & 3, bb = e & 3;
    xs[pl][e] = x[(((size_t)b*64+cc)*128 + i*4+a_)*128 + j*4+bb];
  }
  __syncthreads();
  int pp = tid >> 5, icp = tid & 31;
  int pix = pix0 + pp; int b = pix >> 10, p = pix & 1023, i = p >> 5, j = p & 31;
  int ic = icp & 15;
  const float* wsrc = ((icp < 16) ? wp : wg) + ic*1024;
  float acc = 0.f;
#pragma unroll 8
  for (int k4=0; k4<256; ++k4) {
    float4 xv = *(const float4*)(&xs[pp][k4*4]);
    float4 wv = *(const float4*)(wsrc + k4*4);
    acc += xv.x*wv.x + xv.y*wv.y + xv.z*wv.z + xv.w*wv.w;
  }
  if (icp < 16)
    phi[(((size_t)(b*38 + i+3)*40) + (j+3))*16 + ic] = f2bf(acc + bp[ic]);
  else
    gt[(((size_t)b*16+ic)*38 + i+3)*40 + (j+3)] = acc + bg[ic];
}

__global__ void k_prep_all(const float* __restrict__ x,
                           const float* __restrict__ wt, const float* __restrict__ bt,
                           const float* __restrict__ wp0, const float* __restrict__ bp0,
                           const float* __restrict__ wg0, const float* __restrict__ bg0,
                           const float* __restrict__ wp1, const float* __restrict__ bp1,
                           const float* __restrict__ wg1, const float* __restrict__ bg1,
                           const float* __restrict__ wp2, const float* __restrict__ wg2,
                           const float* __restrict__ bp2, const float* __restrict__ bg2,
                           unsigned short* __restrict__ th, unsigned short* __restrict__ ph0,
                           float* __restrict__ gt0,
                           unsigned short* __restrict__ ph1, float* __restrict__ gt1,
                           unsigned short* __restrict__ ph2, float* __restrict__ gt2)
{
  __shared__ __align__(16) char smem[57344];
  int bid = blockIdx.x;
  if (bid < 512)      prep1_body(bid, x, wt,bt, wp0,bp0, wg0,bg0, th, ph0, gt0, smem);
  else if (bid < 640) conv2_body(bid-512, x, wp1,bp1, wg1,bg1, ph1, gt1, smem);
  else                conv4_body(bid-640, x, wp2,wg2, bp2, bg2, ph2, gt2, smem);
}

// ---------------------------------------------------------------------------
// V tile buffer: g8b[b][sh][y][xb][c][32] bf16 (1KB tile per (sh,y,xb)).
// ---------------------------------------------------------------------------
template<int HP, int WX, int HS>
DEV void shift_body(int idx, const float* __restrict__ gt, unsigned short* __restrict__ g8b)
{
  const int XB = HS/32;
  int xkg = idx & 3;
  int c = (idx >> 2) & 15;
  int t = idx >> 6;
  int xb = t % XB; t /= XB;
  int y = t % HP; t /= HP;
  int sh = t & 7; int b = t >> 3;
  const float* src = gt + (((size_t)b*16+c)*HP + y)*WX + xb*32 + xkg*8 + sh;
  unsigned short o[8];
#pragma unroll
  for (int j=0;j<8;++j) o[j] = f2bf(src[j]);
  unsigned short* dst = g8b + ((((size_t)(b*8+sh)*HP + y)*XB + xb)*16 + c)*32 + xkg*8;
  *(uint4*)dst = *(uint4*)&o[0];
}

__global__ void k_shift_all(const float* __restrict__ gt0, const float* __restrict__ gt1,
                            const float* __restrict__ gt2,
                            unsigned short* __restrict__ g80, unsigned short* __restrict__ g81,
                            unsigned short* __restrict__ g82)
{
  const int T0 = 2*8*134*4*16*4;           // 548864
  const int T1 = 2*8*70*2*16*4;            // 143360
  const int T2 = 2*8*38*1*16*4;            // 38912
  int idx = blockIdx.x*256 + threadIdx.x;
  if (idx < T0) { shift_body<134,136,128>(idx, gt0, g80); return; }
  idx -= T0;
  if (idx < T1) { shift_body<70,72,64>(idx, gt1, g81); return; }
  idx -= T1;
  if (idx < T2) { shift_body<38,40,32>(idx, gt2, g82); }
}

// ---------------------------------------------------------------------------
// Flash attention body (round-17 structure, unchanged).
// ---------------------------------------------------------------------------
template<int HS, int LG, int HP, int WX, int CK, int NCH>
DEV void attn_body(int bid, int slot0,
                   const unsigned short* __restrict__ th,
                   const unsigned short* __restrict__ phi,
                   const unsigned short* __restrict__ g8b,
                   unsigned short* __restrict__ accP, float* __restrict__ lP, char* smem)
{
  const int PO = 30464;
  int tid = threadIdx.x;
  int w = tid >> 6, lane = tid & 63, l15 = lane & 15, g = lane >> 4;
  int chunk, b, qt;
  if (NCH == 8) { chunk = bid & 7; b = (bid >> 3) & 1; qt = bid >> 4; }
  else          { chunk = bid & 3; b = (bid >> 2) & 1; qt = bid >> 3; }
  int q0 = qt * 32;
  int slot = slot0 + chunk;

  const char* thB  = (const char*)th  + (size_t)b*134*136*32;
  const char* phiB = (const char*)phi + (size_t)b*HP*WX*32;

  for (int u = tid; u < 7*136*2; u += 512) {
    int half = u & 1; int cu = (u >> 1) % 136; int r = (u >> 1) / 136;
    uint4 v = *(const uint4*)(thB + (((4*qt+2+r)*136 + cu)*32 + half*16));
    int la = (((r*136 + cu)*32) + half*16) ^ (((cu >> 2) & 7) << 4);
    *(uint4*)(smem + la) = v;
  }
  __syncthreads();

  f32x4 acc[2][7];
#pragma unroll
  for (int rt=0;rt<2;++rt)
#pragma unroll
    for (int et=0;et<7;++et) acc[rt][et] = f32x4{0.f,0.f,0.f,0.f};
  float lacc[2][4];
#pragma unroll
  for (int rt=0;rt<2;++rt)
#pragma unroll
    for (int r=0;r<4;++r) lacc[rt][r] = 0.f;

  const int XBv = HS/32;
  const char* g8B  = (const char*)g8b + (size_t)b*8*HP*XBv*1024;
  const int EPL = HP*XBv*1024;
  int laneVb = l15*64 + g*16;
  int xrP = (l15 & 7) << 4;
  int colb = 4*l15 + 2;
  int hb = (g & 1) << 4;
  const bf16x8 ZV = {0,0,0,0,0,0,0,0};
  const int ITERS = CK/256;
  const float SHIFT = 64.0f, CLAMP = 120.0f;

#pragma unroll 1
  for (int it = 0; it < ITERS; ++it) {
    int k0 = chunk*CK + it*256;
    int po = PO + ((it & 1) << 14);
    f32x4 sc[2][2];
#pragma unroll
    for (int rt=0;rt<2;++rt){ sc[rt][0]=f32x4{0.f,0.f,0.f,0.f}; sc[rt][1]=f32x4{0.f,0.f,0.f,0.f}; }
    int kr_w = (k0 + w*32) >> LG;
    int kc_w = (w*32) & (HS-1);
    int base0 = (kr_w*WX + kc_w + l15)*32 + hb;
    int base1 = base0 + 512;
#pragma unroll
    for (int ks=0; ks<25; ++ks) {
      int p0 = 2*ks;
      int p1 = (2*ks+1 > 48) ? 48 : 2*ks+1;
      int dr0 = p0/7, dc0 = p0%7;
      int dr1 = p1/7, dc1 = p1%7;
      int c0 = colb + dc0, c1 = colb + dc1;
      int la0 = ((dr0*136 + c0)*32 + hb) ^ (((c0 >> 2) & 7) << 4);
      int la1 = ((dr1*136 + c1)*32 + hb) ^ (((c1 >> 2) & 7) << 4);
      int laA = (g & 2) ? la1 : la0;
      int KB0 = (dr0*WX + dc0)*32;
      int KB1 = (dr1*WX + dc1)*32;
      int selB = (g & 2) ? KB1 : KB0;
      bf16x8 a0 = *(const bf16x8*)(smem + laA);
      bf16x8 a1 = *(const bf16x8*)(smem + laA + 2048);
      if (ks == 24) {
        bool z = (g & 2) != 0;
        a0 = z ? ZV : a0; a1 = z ? ZV : a1;
      }
      bf16x8 b0 = *(const bf16x8*)(phiB + base0 + selB);
      bf16x8 b1 = *(const bf16x8*)(phiB + base1 + selB);
      sc[0][0] = __builtin_amdgcn_mfma_f32_16x16x32_bf16(a0, b0, sc[0][0], 0,0,0);
      sc[0][1] = __builtin_amdgcn_mfma_f32_16x16x32_bf16(a0, b1, sc[0][1], 0,0,0);
      sc[1][0] = __builtin_amdgcn_mfma_f32_16x16x32_bf16(a1, b0, sc[1][0], 0,0,0);
      sc[1][1] = __builtin_amdgcn_mfma_f32_16x16x32_bf16(a1, b1, sc[1][1], 0,0,0);
    }
#pragma unroll
    for (int rt=0;rt<2;++rt) {
#pragma unroll
      for (int r=0;r<4;++r) {
        float pa = __builtin_amdgcn_exp2f(fminf(sc[rt][0][r] - SHIFT, CLAMP));
        float pb = __builtin_amdgcn_exp2f(fminf(sc[rt][1][r] - SHIFT, CLAMP));
        lacc[rt][r] += pa + pb;
        int q_ = rt*16 + g*4 + r;
        int offa = q_*512 + (w*32 + l15)*2;      offa ^= (q_&7)<<4;
        int offb = q_*512 + (w*32 + 16 + l15)*2; offb ^= (q_&7)<<4;
        *(unsigned short*)(smem + po + offa) = f2bf(pa);
        *(unsigned short*)(smem + po + offb) = f2bf(pb);
      }
    }
    __syncthreads();
    if (w < 7) {
#pragma unroll
      for (int ks2=0; ks2<8; ++ks2) {
        int kk = k0 + ks2*32;
        int krv = kk >> LG;
        int kcb = kk & (HS-1);
        bf16x8 pf[2];
#pragma unroll
        for (int rt=0;rt<2;++rt) {
          int off = (rt*16 + l15)*512 + ks2*64 + g*16;
          off ^= xrP;
          pf[rt] = *(const bf16x8*)(smem + po + off);
        }
        int vb = ((krv + w)*XBv + (kcb >> 5))*1024 + laneVb;
        bf16x8 vf[7];
#pragma unroll
        for (int et=0;et<7;++et) {
          u32x4 t0 = __builtin_nontemporal_load((const u32x4*)(g8B + vb + et*EPL));
          vf[et] = *(bf16x8*)&t0;
        }
        __builtin_amdgcn_s_setprio(1);
#pragma unroll
        for (int rt=0;rt<2;++rt)
#pragma unroll
          for (int et=0;et<7;++et)
            acc[rt][et] = __builtin_amdgcn_mfma_f32_16x16x32_bf16(pf[rt], vf[et], acc[rt][et], 0,0,0);
        __builtin_amdgcn_s_setprio(0);
      }
    }
  }
  if (w < 7) {
    unsigned short* accB = accP +
      ((((size_t)(slot*2 + b)*32 + qt)*7 + w)*14)*256;
#pragma unroll
    for (int rt=0;rt<2;++rt)
#pragma unroll
      for (int et=0;et<7;++et)
#pragma unroll
        for (int r=0;r<4;++r)
          __builtin_nontemporal_store(f2bf(acc[rt][et][r]),
            &accB[(size_t)(rt*7 + et)*256 + r*64 + lane]);
  }
#pragma unroll
  for (int st=1; st<16; st<<=1)
#pragma unroll
    for (int rt=0;rt<2;++rt)
#pragma unroll
      for (int r=0;r<4;++r) lacc[rt][r] += __shfl_xor(lacc[rt][r], st);
  if (l15 == 0) {
#pragma unroll
    for (int rt=0;rt<2;++rt)
#pragma unroll
      for (int r=0;r<4;++r)
        lP[((size_t)((slot*2 + b)*8 + w) << 10) + q0 + rt*16 + g*4 + r] = lacc[rt][r];
  }
}

__global__ void __launch_bounds__(512, 2)
k_attn_all(const unsigned short* __restrict__ th,
           const unsigned short* __restrict__ ph0, const unsigned short* __restrict__ ph1,
           const unsigned short* __restrict__ ph2,
           const unsigned short* __restrict__ g80, const unsigned short* __restrict__ g81,
           const unsigned short* __restrict__ g82,
           unsigned short* __restrict__ accP, float* __restrict__ lP)
{
  __shared__ __align__(16) char smem[30464 + 2*16384];
  int bid = blockIdx.x;
  if (bid < 512)       attn_body<128,7,134,136,2048,8>(bid,      0,  th, ph0, g80, accP, lP, smem);
  else if (bid < 1024) attn_body<64,6,70,72,512,8>   (bid-512,  8,  th, ph1, g81, accP, lP, smem);
  else                 attn_body<32,5,38,40,256,4>   (bid-1024, 16, th, ph2, g82, accP, lP, smem);
}

// ---------------------------------------------------------------------------
// lG[sc][b*1024+q] = sum over chunks and waves of lP (all 3 scales)
// ---------------------------------------------------------------------------
__global__ void k_comb1_all(const float* __restrict__ lP, float* __restrict__ lG)
{
  int idx = blockIdx.x*256 + threadIdx.x;
  if (idx >= 3*2048) return;
  int sc = idx >> 11, i2 = idx & 2047;
  int b = i2 >> 10, q = i2 & 1023;
  const int NCH[3] = {8,8,4}, S0[3] = {0,8,16};
  float l = 0.f;
  for (int c=0;c<NCH[sc];++c)
#pragma unroll
    for (int w=0;w<8;++w)
      l += lP[((size_t)(((S0[sc]+c)*2 + b)*8 + w) << 10) + q];
  lG[idx] = l;
}

// ---------------------------------------------------------------------------
// Coalesced comb2 (round-17, unchanged)
// ---------------------------------------------------------------------------
__global__ void k_comb2_all(const unsigned short* __restrict__ accP,
                            const float* __restrict__ lG, float* __restrict__ yvfP)
{
  int t8 = blockIdx.x*256 + threadIdx.x;
  if (t8 >= 3*200704) return;
  int sc = t8 / 200704;
  int rem = t8 - sc*200704;
  int e = rem*8;
  int low = e & 255;
  int r = low >> 6, g = (low >> 4) & 3;
  int tile = e >> 8;
  int et = tile % 7; int tt = tile / 7;
  int rt = tt & 1; tt >>= 1;
  int w = tt % 7; tt /= 7;
  int qt = tt & 31; int b = tt >> 5;
  int bq = (b << 10) + qt*32 + rt*16 + g*4 + r;
  const int NCH[3] = {8,8,4}, S0[3] = {0,8,16};
  float s[8];
#pragma unroll
  for (int u=0;u<8;++u) s[u]=0.f;
  for (int ch=0; ch<NCH[sc]; ++ch) {
    const unsigned short* ap = accP + (size_t)(S0[sc]+ch)*1605632 + e;
    u32x4 v = __builtin_nontemporal_load((const u32x4*)ap);
    const unsigned short* pv = (const unsigned short*)&v;
#pragma unroll
    for (int u=0;u<8;++u) s[u] += bf2f(pv[u]);
  }
  float inv = 1.0f / lG[sc*2048 + bq];
  float* dst = yvfP + (size_t)sc*1605632 + e;
  float4 o0, o1;
  o0.x=s[0]*inv; o0.y=s[1]*inv; o0.z=s[2]*inv; o0.w=s[3]*inv;
  o1.x=s[4]*inv; o1.y=s[5]*inv; o1.z=s[6]*inv; o1.w=s[7]*inv;
  *(float4*)dst = o0; *(float4*)(dst+4) = o1;
}

// ---------------------------------------------------------------------------
// fold from permuted yvfP + /mask + conv1x1(w_out)+b_out + x.
// Channel-split: 256 blocks, block (bid>>7) handles output chs [half*32,+32).
// ---------------------------------------------------------------------------
__global__ void k_foldfinal(const float* __restrict__ yvfP, const float* __restrict__ wo,
                            const float* __restrict__ bo, const float* __restrict__ x,
                            float* __restrict__ out)
{
  __shared__ float wl[32*48];
  int half = blockIdx.x >> 7;
  int pixb = blockIdx.x & 127;
  for (int t = threadIdx.x; t < 32*48; t += 256) wl[t] = wo[half*32*48 + t];
  __syncthreads();
  int idx = pixb*256 + threadIdx.x;
  int j = idx & 127; int t = idx >> 7; int i = t & 127; int b = t >> 7;

  int drs[2], qis[2], cnti=0;
  int dcs[2], qjs[2], cntj=0;
#pragma unroll
  for (int dr=0; dr<7; ++dr) {
    int tr = i + 3 - dr;
    if (tr >= 0 && (tr & 3) == 0 && (tr >> 2) < 32) { drs[cnti]=dr; qis[cnti]=tr>>2; ++cnti; }
  }
#pragma unroll
  for (int dc=0; dc<7; ++dc) {
    int tc = j + 3 - dc;
    if (tc >= 0 && (tc & 3) == 0 && (tc >> 2) < 32) { dcs[cntj]=dc; qjs[cntj]=tc>>2; ++cntj; }
  }
  float inv = 1.0f / (float)(cnti*cntj);

  float y[48];
#pragma unroll
  for (int sc=0; sc<3; ++sc) {
    const float* yb = yvfP + (size_t)sc*1605632;
    float a[16];
#pragma unroll
    for (int c=0;c<16;++c) a[c]=0.f;
    for (int u=0; u<cnti; ++u) {
      for (int v=0; v<cntj; ++v) {
        int q = qis[u]*32 + qjs[v];
        int qt = q >> 5, rt = (q >> 4) & 1, gg = (q >> 2) & 3, rr = q & 3;
        int off = ((((b*32 + qt)*7 + drs[u])*2 + rt)*7 + dcs[v])*256 + rr*64 + gg*16;
        const float* src = yb + off;
        float4 v0 = *(const float4*)(src);
        float4 v1 = *(const float4*)(src+4);
        float4 v2 = *(const float4*)(src+8);
        float4 v3 = *(const float4*)(src+12);
        a[0]+=v0.x; a[1]+=v0.y; a[2]+=v0.z; a[3]+=v0.w;
        a[4]+=v1.x; a[5]+=v1.y; a[6]+=v1.z; a[7]+=v1.w;
        a[8]+=v2.x; a[9]+=v2.y; a[10]+=v2.z; a[11]+=v2.w;
        a[12]+=v3.x; a[13]+=v3.y; a[14]+=v3.z; a[15]+=v3.w;
      }
    }
#pragma unroll
    for (int c=0;c<16;++c) y[sc*16+c] = a[c]*inv;
  }

  const float* xb = x + (size_t)b*64*16384 + i*128 + j;
  float* ob = out + (size_t)b*64*16384 + i*128 + j;
  for (int o=0;o<32;++o) {
    int oc = half*32 + o;
    float s = bo[oc];
#pragma unroll
    for (int c=0;c<48;++c) s += y[c]*wl[o*48+c];
    ob[(size_t)oc*16384] = s + xb[(size_t)oc*16384];
  }
}

// ---------------------------------------------------------------------------
extern "C" void kernel_launch(void* const* d_in, const int* in_sizes, int n_in,
                              void* d_out, int out_size, void* d_ws, size_t ws_size,
                              hipStream_t stream)
{
  const float* x  = (const float*)d_in[0];
  const float* wt = (const float*)d_in[1];
  const float* bt = (const float*)d_in[2];
  const float* wp0= (const float*)d_in[3];
  const float* bp0= (const float*)d_in[4];
  const float* wg0= (const float*)d_in[5];
  const float* bg0= (const float*)d_in[6];
  const float* wp1= (const float*)d_in[7];
  const float* bp1= (const float*)d_in[8];
  const float* wg1= (const float*)d_in[9];
  const float* bg1= (const float*)d_in[10];
  const float* wp2= (const float*)d_in[11];
  const float* bp2= (const float*)d_in[12];
  const float* wg2= (const float*)d_in[13];
  const float* bg2= (const float*)d_in[14];
  const float* wo = (const float*)d_in[15];
  const float* bo = (const float*)d_in[16];
  float* out = (float*)d_out;
  (void)in_sizes; (void)n_in; (void)out_size; (void)ws_size;

  char* ws = (char*)d_ws;
  size_t off = 0;
  auto alloc = [&](size_t bytes)->char* { char* p = ws + off; off += (bytes + 255) & ~(size_t)255; return p; };
  unsigned short* th  = (unsigned short*)alloc(2ull*134*136*16*2);
  unsigned short* ph0 = (unsigned short*)alloc(2ull*134*136*16*2);
  unsigned short* ph1 = (unsigned short*)alloc(2ull*70*72*16*2);
  unsigned short* ph2 = (unsigned short*)alloc(2ull*38*40*16*2);
  float* gt0 = (float*)alloc(2ull*16*134*136*4);
  float* gt1 = (float*)alloc(2ull*16*70*72*4);
  float* gt2 = (float*)alloc(2ull*16*38*40*4);
  size_t zeroBytes = off;                      // th..gt2 contiguous prefix
  unsigned short* g80 = (unsigned short*)alloc(2ull*8*134*4*512*2);
  unsigned short* g81 = (unsigned short*)alloc(2ull*8*70*2*512*2);
  unsigned short* g82 = (unsigned short*)alloc(2ull*8*38*1*512*2);
  float* lP  = (float*)alloc(20ull*2*8*1024*4);
  float* lG  = (float*)alloc(3ull*2048*4);
  unsigned short* accP = (unsigned short*)alloc(20ull*2048*784*2);
  float* yvfP = (float*)alloc(3ull*2048*784*4);

  int n16 = (int)(zeroBytes/16);
  k_zero<<<(n16+255)/256,256,0,stream>>>((uint4*)ws, n16);
  k_prep_all<<<896,256,0,stream>>>(x, wt,bt, wp0,bp0,wg0,bg0, wp1,bp1,wg1,bg1,
                                   wp2,wg2, bp2,bg2, th,ph0,gt0, ph1,gt1, ph2,gt2);
  k_shift_all<<<(548864+143360+38912+255)/256,256,0,stream>>>(gt0,gt1,gt2, g80,g81,g82);
  k_attn_all<<<1280,512,0,stream>>>(th, ph0,ph1,ph2, g80,g81,g82, accP, lP);
  k_comb1_all<<<(3*2048+255)/256,256,0,stream>>>(lP, lG);
  k_comb2_all<<<(3*200704+255)/256,256,0,stream>>>(accP, lG, yvfP);
  k_foldfinal<<<256,256,0,stream>>>(yvfP, wo, bo, x, out);
}

// Round 21
// 412.359 us; speedup vs baseline: 1.3926x; 1.0029x over previous
//
#include <hip/hip_runtime.h>
#include <stdint.h>

typedef __attribute__((ext_vector_type(8))) short bf16x8;
typedef __attribute__((ext_vector_type(4))) float f32x4;
typedef __attribute__((ext_vector_type(4))) unsigned int u32x4;

#define DEV __device__ __forceinline__

DEV float bf2f(unsigned short u){ union{unsigned int i; float f;} v; v.i=((unsigned int)u)<<16; return v.f; }
DEV unsigned short f2bf(float f){ union{float f; unsigned int i;} v; v.f=f; unsigned int x=v.i;
  return (unsigned short)((x + 0x7fffu + ((x>>16)&1u)) >> 16); }

// ---------------------------------------------------------------------------
// Zero the padded-border prefix (th..gt2). MUST run before k_prep_all.
// ---------------------------------------------------------------------------
__global__ void k_zero(uint4* __restrict__ p, int n16)
{
  int idx = blockIdx.x*256 + threadIdx.x;
  if (idx < n16) p[idx] = uint4{0,0,0,0};
}

// ---------------------------------------------------------------------------
// prep bodies (shared LDS buffer, routed by block range in k_prep_all).
// ---------------------------------------------------------------------------
DEV void prep1_body(int bid, const float* __restrict__ x,
                    const float* __restrict__ wt, const float* __restrict__ bt,
                    const float* __restrict__ wp, const float* __restrict__ bp,
                    const float* __restrict__ wg, const float* __restrict__ bg,
                    unsigned short* __restrict__ th, unsigned short* __restrict__ ph,
                    float* __restrict__ gt, char* smemc)
{
  float (*red)[64][48] = (float(*)[64][48])smemc;
  float* wl = (float*)(smemc + 36864);     // wt[1024] | wp[1024] | wg[1024]
  int tid = threadIdx.x;
  for (int u = tid; u < 768; u += 256) {
    float4 v;
    if (u < 256) v = ((const float4*)wt)[u];
    else if (u < 512) v = ((const float4*)wp)[u-256];
    else v = ((const float4*)wg)[u-512];
    ((float4*)wl)[u] = v;
  }
  __syncthreads();
  int grp = tid >> 6, pixl = tid & 63;
  int pix = bid*64 + pixl;                 // [0, 32768)
  int b = pix >> 14, p = pix & 16383, i = p >> 7, j = p & 127;
  float a[48];
#pragma unroll
  for (int c=0;c<48;++c) a[c]=0.f;
  const float* xb = x + (size_t)b*64*16384 + p;
#pragma unroll
  for (int c4=0; c4<4; ++c4) {
    int cc = grp*16 + c4*4;
    float xv[4];
#pragma unroll
    for (int u=0;u<4;++u) xv[u] = xb[(size_t)(cc+u)*16384];
#pragma unroll
    for (int ic=0;ic<16;++ic) {
      float4 w0 = *(const float4*)(wl + ic*64 + cc);
      float4 w1 = *(const float4*)(wl + 1024 + ic*64 + cc);
      float4 w2 = *(const float4*)(wl + 2048 + ic*64 + cc);
      a[ic]    += xv[0]*w0.x + xv[1]*w0.y + xv[2]*w0.z + xv[3]*w0.w;
      a[16+ic] += xv[0]*w1.x + xv[1]*w1.y + xv[2]*w1.z + xv[3]*w1.w;
      a[32+ic] += xv[0]*w2.x + xv[1]*w2.y + xv[2]*w2.z + xv[3]*w2.w;
    }
  }
  if (grp) {
#pragma unroll
    for (int c=0;c<48;++c) red[grp-1][pixl][c] = a[c];
  }
  __syncthreads();
  if (grp == 0) {
#pragma unroll
    for (int c=0;c<48;++c) a[c] += red[0][pixl][c] + red[1][pixl][c] + red[2][pixl][c];
    const float TEMPC = 14.426950408889634f;
    unsigned short o[16];
#pragma unroll
    for (int ic=0;ic<16;++ic) o[ic] = f2bf((a[ic]+bt[ic])*TEMPC);
    uint4* d0 = (uint4*)(th + ((size_t)(b*134 + i+3)*136 + (j+3))*16);
    d0[0]=*(uint4*)&o[0]; d0[1]=*(uint4*)&o[8];
#pragma unroll
    for (int ic=0;ic<16;++ic) o[ic] = f2bf(a[16+ic]+bp[ic]);
    uint4* d1 = (uint4*)(ph + ((size_t)(b*134 + i+3)*136 + (j+3))*16);
    d1[0]=*(uint4*)&o[0]; d1[1]=*(uint4*)&o[8];
#pragma unroll
    for (int ic=0;ic<16;++ic)
      gt[(((size_t)b*16+ic)*134 + i+3)*136 + (j+3)] = a[32+ic]+bg[ic];
  }
}

DEV void conv2_body(int bid, const float* __restrict__ x,
                    const float* __restrict__ wp, const float* __restrict__ bp,
                    const float* __restrict__ wg, const float* __restrict__ bg,
                    unsigned short* __restrict__ phi, float* __restrict__ gt, char* smemc)
{
  float (*red)[64][32] = (float(*)[64][32])smemc;
  float* wl = (float*)(smemc + 24576);     // wp[4096] | wg[4096]
  int tid = threadIdx.x;
  for (int u = tid; u < 2048; u += 256) {
    float4 v = (u < 1024) ? ((const float4*)wp)[u] : ((const float4*)wg)[u-1024];
    ((float4*)wl)[u] = v;
  }
  __syncthreads();
  int grp = tid >> 6, pixl = tid & 63;
  int pix = bid*64 + pixl;                 // [0, 8192)
  int b = pix >> 12, p = pix & 4095, i = p >> 6, j = p & 63;
  float a[32];
#pragma unroll
  for (int c=0;c<32;++c) a[c]=0.f;
  const float* xb = x + (size_t)b*64*16384 + (i*2)*128 + j*2;
#pragma unroll
  for (int c0=0; c0<16; ++c0) {
    int cc = grp*16 + c0;
    const float* xp = xb + (size_t)cc*16384;
    float xv[4];
    xv[0]=xp[0]; xv[1]=xp[1]; xv[2]=xp[128]; xv[3]=xp[129];
#pragma unroll
    for (int ic=0;ic<16;++ic) {
      float4 w0 = *(const float4*)(wl + (ic*64+cc)*4);
      float4 w1 = *(const float4*)(wl + 4096 + (ic*64+cc)*4);
      a[ic]    += xv[0]*w0.x + xv[1]*w0.y + xv[2]*w0.z + xv[3]*w0.w;
      a[16+ic] += xv[0]*w1.x + xv[1]*w1.y + xv[2]*w1.z + xv[3]*w1.w;
    }
  }
  if (grp) {
#pragma unroll
    for (int c=0;c<32;++c) red[grp-1][pixl][c] = a[c];
  }
  __syncthreads();
  if (grp == 0) {
#pragma unroll
    for (int c=0;c<32;++c) a[c] += red[0][pixl][c] + red[1][pixl][c] + red[2][pixl][c];
    unsigned short o[16];
#pragma unroll
    for (int ic=0;ic<16;++ic) o[ic] = f2bf(a[ic]+bp[ic]);
    uint4* d1 = (uint4*)(phi + ((size_t)(b*70 + i+3)*72 + (j+3))*16);
    d1[0]=*(uint4*)&o[0]; d1[1]=*(uint4*)&o[8];
#pragma unroll
    for (int ic=0;ic<16;++ic)
      gt[(((size_t)b*16+ic)*70 + i+3)*72 + (j+3)] = a[16+ic]+bg[ic];
  }
}

DEV void conv4_body(int bid, const float* __restrict__ x,
                    const float* __restrict__ wp, const float* __restrict__ wg,
                    const float* __restrict__ bp, const float* __restrict__ bg,
                    unsigned short* __restrict__ phi, float* __restrict__ gt, char* smemc)
{
  float (*xs)[1028] = (float(*)[1028])smemc;
  int tid = threadIdx.x;
  int pix0 = bid*8;                        // [0,2048) step 8
  for (int idx = tid; idx < 8*1024; idx += 256) {
    int pl = idx >> 10, e = idx & 1023;
    int pix = pix0 + pl; int b = pix >> 10, p = pix & 1023, i = p >> 5, j = p & 31;
    int cc = e >> 4, a_ = (e >> 2) & 3, bb = e & 3;
    xs[pl][e] = x[(((size_t)b*64+cc)*128 + i*4+a_)*128 + j*4+bb];
  }
  __syncthreads();
  int pp = tid >> 5, icp = tid & 31;
  int pix = pix0 + pp; int b = pix >> 10, p = pix & 1023, i = p >> 5, j = p & 31;
  int ic = icp & 15;
  const float* wsrc = ((icp < 16) ? wp : wg) + ic*1024;
  float acc = 0.f;
#pragma unroll 8
  for (int k4=0; k4<256; ++k4) {
    float4 xv = *(const float4*)(&xs[pp][k4*4]);
    float4 wv = *(const float4*)(wsrc + k4*4);
    acc += xv.x*wv.x + xv.y*wv.y + xv.z*wv.z + xv.w*wv.w;
  }
  if (icp < 16)
    phi[(((size_t)(b*38 + i+3)*40) + (j+3))*16 + ic] = f2bf(acc + bp[ic]);
  else
    gt[(((size_t)b*16+ic)*38 + i+3)*40 + (j+3)] = acc + bg[ic];
}

__global__ void k_prep_all(const float* __restrict__ x,
                           const float* __restrict__ wt, const float* __restrict__ bt,
                           const float* __restrict__ wp0, const float* __restrict__ bp0,
                           const float* __restrict__ wg0, const float* __restrict__ bg0,
                           const float* __restrict__ wp1, const float* __restrict__ bp1,
                           const float* __restrict__ wg1, const float* __restrict__ bg1,
                           const float* __restrict__ wp2, const float* __restrict__ wg2,
                           const float* __restrict__ bp2, const float* __restrict__ bg2,
                           unsigned short* __restrict__ th, unsigned short* __restrict__ ph0,
                           float* __restrict__ gt0,
                           unsigned short* __restrict__ ph1, float* __restrict__ gt1,
                           unsigned short* __restrict__ ph2, float* __restrict__ gt2)
{
  __shared__ __align__(16) char smem[57344];
  int bid = blockIdx.x;
  if (bid < 512)      prep1_body(bid, x, wt,bt, wp0,bp0, wg0,bg0, th, ph0, gt0, smem);
  else if (bid < 640) conv2_body(bid-512, x, wp1,bp1, wg1,bg1, ph1, gt1, smem);
  else                conv4_body(bid-640, x, wp2,wg2, bp2, bg2, ph2, gt2, smem);
}

// ---------------------------------------------------------------------------
// V tile buffer: g8b[b][sh][y][xb][c][32] bf16 (1KB tile per (sh,y,xb)).
// ---------------------------------------------------------------------------
template<int HP, int WX, int HS>
DEV void shift_body(int idx, const float* __restrict__ gt, unsigned short* __restrict__ g8b)
{
  const int XB = HS/32;
  int xkg = idx & 3;
  int c = (idx >> 2) & 15;
  int t = idx >> 6;
  int xb = t % XB; t /= XB;
  int y = t % HP; t /= HP;
  int sh = t & 7; int b = t >> 3;
  const float* src = gt + (((size_t)b*16+c)*HP + y)*WX + xb*32 + xkg*8 + sh;
  unsigned short o[8];
#pragma unroll
  for (int j=0;j<8;++j) o[j] = f2bf(src[j]);
  unsigned short* dst = g8b + ((((size_t)(b*8+sh)*HP + y)*XB + xb)*16 + c)*32 + xkg*8;
  *(uint4*)dst = *(uint4*)&o[0];
}

__global__ void k_shift_all(const float* __restrict__ gt0, const float* __restrict__ gt1,
                            const float* __restrict__ gt2,
                            unsigned short* __restrict__ g80, unsigned short* __restrict__ g81,
                            unsigned short* __restrict__ g82)
{
  const int T0 = 2*8*134*4*16*4;           // 548864
  const int T1 = 2*8*70*2*16*4;            // 143360
  const int T2 = 2*8*38*1*16*4;            // 38912
  int idx = blockIdx.x*256 + threadIdx.x;
  if (idx < T0) { shift_body<134,136,128>(idx, gt0, g80); return; }
  idx -= T0;
  if (idx < T1) { shift_body<70,72,64>(idx, gt1, g81); return; }
  idx -= T1;
  if (idx < T2) { shift_body<38,40,32>(idx, gt2, g82); }
}

// ---------------------------------------------------------------------------
// Flash attention body with ROTATED software pipeline:
//   QK(0);Pwrite(0);barrier; { PV(t-1); QK(t); Pwrite(t); barrier }; PV(last)
// PV(t-1) and QK(t) are contiguous straight-line code in ONE barrier-free
// region -> the scheduler can interleave QK's phi/theta loads under PV's
// MFMA burst. P double-buffer makes this hazard-free with 1 barrier/iter.
// ---------------------------------------------------------------------------
template<int HS, int LG, int HP, int WX, int CK, int NCH>
DEV void attn_body(int bid, int slot0,
                   const unsigned short* __restrict__ th,
                   const unsigned short* __restrict__ phi,
                   const unsigned short* __restrict__ g8b,
                   unsigned short* __restrict__ accP, float* __restrict__ lP, char* smem)
{
  const int PO = 30464;
  int tid = threadIdx.x;
  int w = tid >> 6, lane = tid & 63, l15 = lane & 15, g = lane >> 4;
  int chunk, b, qt;
  if (NCH == 8) { chunk = bid & 7; b = (bid >> 3) & 1; qt = bid >> 4; }
  else          { chunk = bid & 3; b = (bid >> 2) & 1; qt = bid >> 3; }
  int q0 = qt * 32;
  int slot = slot0 + chunk;

  const char* thB  = (const char*)th  + (size_t)b*134*136*32;
  const char* phiB = (const char*)phi + (size_t)b*HP*WX*32;

  for (int u = tid; u < 7*136*2; u += 512) {
    int half = u & 1; int cu = (u >> 1) % 136; int r = (u >> 1) / 136;
    uint4 v = *(const uint4*)(thB + (((4*qt+2+r)*136 + cu)*32 + half*16));
    int la = (((r*136 + cu)*32) + half*16) ^ (((cu >> 2) & 7) << 4);
    *(uint4*)(smem + la) = v;
  }
  __syncthreads();

  f32x4 acc[2][7];
#pragma unroll
  for (int rt=0;rt<2;++rt)
#pragma unroll
    for (int et=0;et<7;++et) acc[rt][et] = f32x4{0.f,0.f,0.f,0.f};
  float lacc[2][4];
#pragma unroll
  for (int rt=0;rt<2;++rt)
#pragma unroll
    for (int r=0;r<4;++r) lacc[rt][r] = 0.f;

  const int XBv = HS/32;
  const char* g8B  = (const char*)g8b + (size_t)b*8*HP*XBv*1024;
  const int EPL = HP*XBv*1024;
  int laneVb = l15*64 + g*16;
  int xrP = (l15 & 7) << 4;
  int colb = 4*l15 + 2;
  int hb = (g & 1) << 4;
  const bf16x8 ZV = {0,0,0,0,0,0,0,0};
  const int ITERS = CK/256;
  const float SHIFT = 64.0f, CLAMP = 120.0f;

  // ---- QK(it): scores + P-write into buf it&1, lacc update ----
  auto QK = [&](int it) {
    int k0 = chunk*CK + it*256;
    int po = PO + ((it & 1) << 14);
    f32x4 sc[2][2];
#pragma unroll
    for (int rt=0;rt<2;++rt){ sc[rt][0]=f32x4{0.f,0.f,0.f,0.f}; sc[rt][1]=f32x4{0.f,0.f,0.f,0.f}; }
    int kr_w = (k0 + w*32) >> LG;
    int kc_w = (w*32) & (HS-1);
    int base0 = (kr_w*WX + kc_w + l15)*32 + hb;
    int base1 = base0 + 512;
#pragma unroll
    for (int ks=0; ks<25; ++ks) {
      int p0 = 2*ks;
      int p1 = (2*ks+1 > 48) ? 48 : 2*ks+1;
      int dr0 = p0/7, dc0 = p0%7;
      int dr1 = p1/7, dc1 = p1%7;
      int c0 = colb + dc0, c1 = colb + dc1;
      int la0 = ((dr0*136 + c0)*32 + hb) ^ (((c0 >> 2) & 7) << 4);
      int la1 = ((dr1*136 + c1)*32 + hb) ^ (((c1 >> 2) & 7) << 4);
      int laA = (g & 2) ? la1 : la0;
      int KB0 = (dr0*WX + dc0)*32;
      int KB1 = (dr1*WX + dc1)*32;
      int selB = (g & 2) ? KB1 : KB0;
      bf16x8 a0 = *(const bf16x8*)(smem + laA);
      bf16x8 a1 = *(const bf16x8*)(smem + laA + 2048);
      if (ks == 24) {
        bool z = (g & 2) != 0;
        a0 = z ? ZV : a0; a1 = z ? ZV : a1;
      }
      bf16x8 b0 = *(const bf16x8*)(phiB + base0 + selB);
      bf16x8 b1 = *(const bf16x8*)(phiB + base1 + selB);
      sc[0][0] = __builtin_amdgcn_mfma_f32_16x16x32_bf16(a0, b0, sc[0][0], 0,0,0);
      sc[0][1] = __builtin_amdgcn_mfma_f32_16x16x32_bf16(a0, b1, sc[0][1], 0,0,0);
      sc[1][0] = __builtin_amdgcn_mfma_f32_16x16x32_bf16(a1, b0, sc[1][0], 0,0,0);
      sc[1][1] = __builtin_amdgcn_mfma_f32_16x16x32_bf16(a1, b1, sc[1][1], 0,0,0);
    }
#pragma unroll
    for (int rt=0;rt<2;++rt) {
#pragma unroll
      for (int r=0;r<4;++r) {
        float pa = __builtin_amdgcn_exp2f(fminf(sc[rt][0][r] - SHIFT, CLAMP));
        float pb = __builtin_amdgcn_exp2f(fminf(sc[rt][1][r] - SHIFT, CLAMP));
        lacc[rt][r] += pa + pb;
        int q_ = rt*16 + g*4 + r;
        int offa = q_*512 + (w*32 + l15)*2;      offa ^= (q_&7)<<4;
        int offb = q_*512 + (w*32 + 16 + l15)*2; offb ^= (q_&7)<<4;
        *(unsigned short*)(smem + po + offa) = f2bf(pa);
        *(unsigned short*)(smem + po + offb) = f2bf(pb);
      }
    }
  };

  // ---- PV(it): accumulate from buf it&1 (waves 0-6) ----
  auto PV = [&](int it) {
    if (w >= 7) return;
    int k0 = chunk*CK + it*256;
    int po = PO + ((it & 1) << 14);
#pragma unroll
    for (int ks2=0; ks2<8; ++ks2) {
      int kk = k0 + ks2*32;
      int krv = kk >> LG;
      int kcb = kk & (HS-1);
      bf16x8 pf[2];
#pragma unroll
      for (int rt=0;rt<2;++rt) {
        int off = (rt*16 + l15)*512 + ks2*64 + g*16;
        off ^= xrP;
        pf[rt] = *(const bf16x8*)(smem + po + off);
      }
      int vb = ((krv + w)*XBv + (kcb >> 5))*1024 + laneVb;
      bf16x8 vf[7];
#pragma unroll
      for (int et=0;et<7;++et) {
        u32x4 t0 = __builtin_nontemporal_load((const u32x4*)(g8B + vb + et*EPL));
        vf[et] = *(bf16x8*)&t0;
      }
      __builtin_amdgcn_s_setprio(1);
#pragma unroll
      for (int rt=0;rt<2;++rt)
#pragma unroll
        for (int et=0;et<7;++et)
          acc[rt][et] = __builtin_amdgcn_mfma_f32_16x16x32_bf16(pf[rt], vf[et], acc[rt][et], 0,0,0);
      __builtin_amdgcn_s_setprio(0);
    }
  };

  QK(0);
  __syncthreads();
#pragma unroll 1
  for (int it = 1; it < ITERS; ++it) {
    PV(it-1);          // MFMA burst on buf (it-1)&1 ...
    QK(it);            // ... interleaved with next-tile loads into buf it&1
    __syncthreads();
  }
  PV(ITERS-1);

  if (w < 7) {
    unsigned short* accB = accP +
      ((((size_t)(slot*2 + b)*32 + qt)*7 + w)*14)*256;
#pragma unroll
    for (int rt=0;rt<2;++rt)
#pragma unroll
      for (int et=0;et<7;++et)
#pragma unroll
        for (int r=0;r<4;++r)
          __builtin_nontemporal_store(f2bf(acc[rt][et][r]),
            &accB[(size_t)(rt*7 + et)*256 + r*64 + lane]);
  }
#pragma unroll
  for (int st=1; st<16; st<<=1)
#pragma unroll
    for (int rt=0;rt<2;++rt)
#pragma unroll
      for (int r=0;r<4;++r) lacc[rt][r] += __shfl_xor(lacc[rt][r], st);
  if (l15 == 0) {
#pragma unroll
    for (int rt=0;rt<2;++rt)
#pragma unroll
      for (int r=0;r<4;++r)
        lP[((size_t)((slot*2 + b)*8 + w) << 10) + q0 + rt*16 + g*4 + r] = lacc[rt][r];
  }
}

__global__ void __launch_bounds__(512, 2)
k_attn_all(const unsigned short* __restrict__ th,
           const unsigned short* __restrict__ ph0, const unsigned short* __restrict__ ph1,
           const unsigned short* __restrict__ ph2,
           const unsigned short* __restrict__ g80, const unsigned short* __restrict__ g81,
           const unsigned short* __restrict__ g82,
           unsigned short* __restrict__ accP, float* __restrict__ lP)
{
  __shared__ __align__(16) char smem[30464 + 2*16384];
  int bid = blockIdx.x;
  if (bid < 512)       attn_body<128,7,134,136,2048,8>(bid,      0,  th, ph0, g80, accP, lP, smem);
  else if (bid < 1024) attn_body<64,6,70,72,512,8>   (bid-512,  8,  th, ph1, g81, accP, lP, smem);
  else                 attn_body<32,5,38,40,256,4>   (bid-1024, 16, th, ph2, g82, accP, lP, smem);
}

// ---------------------------------------------------------------------------
// lG[sc][b*1024+q] = sum over chunks and waves of lP (all 3 scales)
// ---------------------------------------------------------------------------
__global__ void k_comb1_all(const float* __restrict__ lP, float* __restrict__ lG)
{
  int idx = blockIdx.x*256 + threadIdx.x;
  if (idx >= 3*2048) return;
  int sc = idx >> 11, i2 = idx & 2047;
  int b = i2 >> 10, q = i2 & 1023;
  const int NCH[3] = {8,8,4}, S0[3] = {0,8,16};
  float l = 0.f;
  for (int c=0;c<NCH[sc];++c)
#pragma unroll
    for (int w=0;w<8;++w)
      l += lP[((size_t)(((S0[sc]+c)*2 + b)*8 + w) << 10) + q];
  lG[idx] = l;
}

// ---------------------------------------------------------------------------
// Coalesced comb2 (unchanged)
// ---------------------------------------------------------------------------
__global__ void k_comb2_all(const unsigned short* __restrict__ accP,
                            const float* __restrict__ lG, float* __restrict__ yvfP)
{
  int t8 = blockIdx.x*256 + threadIdx.x;
  if (t8 >= 3*200704) return;
  int sc = t8 / 200704;
  int rem = t8 - sc*200704;
  int e = rem*8;
  int low = e & 255;
  int r = low >> 6, g = (low >> 4) & 3;
  int tile = e >> 8;
  int et = tile % 7; int tt = tile / 7;
  int rt = tt & 1; tt >>= 1;
  int w = tt % 7; tt /= 7;
  int qt = tt & 31; int b = tt >> 5;
  int bq = (b << 10) + qt*32 + rt*16 + g*4 + r;
  const int NCH[3] = {8,8,4}, S0[3] = {0,8,16};
  float s[8];
#pragma unroll
  for (int u=0;u<8;++u) s[u]=0.f;
  for (int ch=0; ch<NCH[sc]; ++ch) {
    const unsigned short* ap = accP + (size_t)(S0[sc]+ch)*1605632 + e;
    u32x4 v = __builtin_nontemporal_load((const u32x4*)ap);
    const unsigned short* pv = (const unsigned short*)&v;
#pragma unroll
    for (int u=0;u<8;++u) s[u] += bf2f(pv[u]);
  }
  float inv = 1.0f / lG[sc*2048 + bq];
  float* dst = yvfP + (size_t)sc*1605632 + e;
  float4 o0, o1;
  o0.x=s[0]*inv; o0.y=s[1]*inv; o0.z=s[2]*inv; o0.w=s[3]*inv;
  o1.x=s[4]*inv; o1.y=s[5]*inv; o1.z=s[6]*inv; o1.w=s[7]*inv;
  *(float4*)dst = o0; *(float4*)(dst+4) = o1;
}

// ---------------------------------------------------------------------------
// fold from permuted yvfP + /mask + conv1x1(w_out)+b_out + x (channel-split)
// ---------------------------------------------------------------------------
__global__ void k_foldfinal(const float* __restrict__ yvfP, const float* __restrict__ wo,
                            const float* __restrict__ bo, const float* __restrict__ x,
                            float* __restrict__ out)
{
  __shared__ float wl[32*48];
  int half = blockIdx.x >> 7;
  int pixb = blockIdx.x & 127;
  for (int t = threadIdx.x; t < 32*48; t += 256) wl[t] = wo[half*32*48 + t];
  __syncthreads();
  int idx = pixb*256 + threadIdx.x;
  int j = idx & 127; int t = idx >> 7; int i = t & 127; int b = t >> 7;

  int drs[2], qis[2], cnti=0;
  int dcs[2], qjs[2], cntj=0;
#pragma unroll
  for (int dr=0; dr<7; ++dr) {
    int tr = i + 3 - dr;
    if (tr >= 0 && (tr & 3) == 0 && (tr >> 2) < 32) { drs[cnti]=dr; qis[cnti]=tr>>2; ++cnti; }
  }
#pragma unroll
  for (int dc=0; dc<7; ++dc) {
    int tc = j + 3 - dc;
    if (tc >= 0 && (tc & 3) == 0 && (tc >> 2) < 32) { dcs[cntj]=dc; qjs[cntj]=tc>>2; ++cntj; }
  }
  float inv = 1.0f / (float)(cnti*cntj);

  float y[48];
#pragma unroll
  for (int sc=0; sc<3; ++sc) {
    const float* yb = yvfP + (size_t)sc*1605632;
    float a[16];
#pragma unroll
    for (int c=0;c<16;++c) a[c]=0.f;
    for (int u=0; u<cnti; ++u) {
      for (int v=0; v<cntj; ++v) {
        int q = qis[u]*32 + qjs[v];
        int qt = q >> 5, rt = (q >> 4) & 1, gg = (q >> 2) & 3, rr = q & 3;
        int off = ((((b*32 + qt)*7 + drs[u])*2 + rt)*7 + dcs[v])*256 + rr*64 + gg*16;
        const float* src = yb + off;
        float4 v0 = *(const float4*)(src);
        float4 v1 = *(const float4*)(src+4);
        float4 v2 = *(const float4*)(src+8);
        float4 v3 = *(const float4*)(src+12);
        a[0]+=v0.x; a[1]+=v0.y; a[2]+=v0.z; a[3]+=v0.w;
        a[4]+=v1.x; a[5]+=v1.y; a[6]+=v1.z; a[7]+=v1.w;
        a[8]+=v2.x; a[9]+=v2.y; a[10]+=v2.z; a[11]+=v2.w;
        a[12]+=v3.x; a[13]+=v3.y; a[14]+=v3.z; a[15]+=v3.w;
      }
    }
#pragma unroll
    for (int c=0;c<16;++c) y[sc*16+c] = a[c]*inv;
  }

  const float* xb = x + (size_t)b*64*16384 + i*128 + j;
  float* ob = out + (size_t)b*64*16384 + i*128 + j;
  for (int o=0;o<32;++o) {
    int oc = half*32 + o;
    float s = bo[oc];
#pragma unroll
    for (int c=0;c<48;++c) s += y[c]*wl[o*48+c];
    ob[(size_t)oc*16384] = s + xb[(size_t)oc*16384];
  }
}

// ---------------------------------------------------------------------------
extern "C" void kernel_launch(void* const* d_in, const int* in_sizes, int n_in,
                              void* d_out, int out_size, void* d_ws, size_t ws_size,
                              hipStream_t stream)
{
  const float* x  = (const float*)d_in[0];
  const float* wt = (const float*)d_in[1];
  const float* bt = (const float*)d_in[2];
  const float* wp0= (const float*)d_in[3];
  const float* bp0= (const float*)d_in[4];
  const float* wg0= (const float*)d_in[5];
  const float* bg0= (const float*)d_in[6];
  const float* wp1= (const float*)d_in[7];
  const float* bp1= (const float*)d_in[8];
  const float* wg1= (const float*)d_in[9];
  const float* bg1= (const float*)d_in[10];
  const float* wp2= (const float*)d_in[11];
  const float* bp2= (const float*)d_in[12];
  const float* wg2= (const float*)d_in[13];
  const float* bg2= (const float*)d_in[14];
  const float* wo = (const float*)d_in[15];
  const float* bo = (const float*)d_in[16];
  float* out = (float*)d_out;
  (void)in_sizes; (void)n_in; (void)out_size; (void)ws_size;

  char* ws = (char*)d_ws;
  size_t off = 0;
  auto alloc = [&](size_t bytes)->char* { char* p = ws + off; off += (bytes + 255) & ~(size_t)255; return p; };
  unsigned short* th  = (unsigned short*)alloc(2ull*134*136*16*2);
  unsigned short* ph0 = (unsigned short*)alloc(2ull*134*136*16*2);
  unsigned short* ph1 = (unsigned short*)alloc(2ull*70*72*16*2);
  unsigned short* ph2 = (unsigned short*)alloc(2ull*38*40*16*2);
  float* gt0 = (float*)alloc(2ull*16*134*136*4);
  float* gt1 = (float*)alloc(2ull*16*70*72*4);
  float* gt2 = (float*)alloc(2ull*16*38*40*4);
  size_t zeroBytes = off;                      // th..gt2 contiguous prefix
  unsigned short* g80 = (unsigned short*)alloc(2ull*8*134*4*512*2);
  unsigned short* g81 = (unsigned short*)alloc(2ull*8*70*2*512*2);
  unsigned short* g82 = (unsigned short*)alloc(2ull*8*38*1*512*2);
  float* lP  = (float*)alloc(20ull*2*8*1024*4);
  float* lG  = (float*)alloc(3ull*2048*4);
  unsigned short* accP = (unsigned short*)alloc(20ull*2048*784*2);
  float* yvfP = (float*)alloc(3ull*2048*784*4);

  int n16 = (int)(zeroBytes/16);
  k_zero<<<(n16+255)/256,256,0,stream>>>((uint4*)ws, n16);
  k_prep_all<<<896,256,0,stream>>>(x, wt,bt, wp0,bp0,wg0,bg0, wp1,bp1,wg1,bg1,
                                   wp2,wg2, bp2,bg2, th,ph0,gt0, ph1,gt1, ph2,gt2);
  k_shift_all<<<(548864+143360+38912+255)/256,256,0,stream>>>(gt0,gt1,gt2, g80,g81,g82);
  k_attn_all<<<1280,512,0,stream>>>(th, ph0,ph1,ph2, g80,g81,g82, accP, lP);
  k_comb1_all<<<(3*2048+255)/256,256,0,stream>>>(lP, lG);
  k_comb2_all<<<(3*200704+255)/256,256,0,stream>>>(accP, lG, yvfP);
  k_foldfinal<<<256,256,0,stream>>>(yvfP, wo, bo, x, out);
}

// Round 22
// 386.880 us; speedup vs baseline: 1.4843x; 1.0659x over previous
//
#include <hip/hip_runtime.h>
#include <stdint.h>

typedef __attribute__((ext_vector_type(8))) short bf16x8;
typedef __attribute__((ext_vector_type(4))) float f32x4;
typedef __attribute__((ext_vector_type(4))) unsigned int u32x4;

#define DEV __device__ __forceinline__

DEV float bf2f(unsigned short u){ union{unsigned int i; float f;} v; v.i=((unsigned int)u)<<16; return v.f; }
DEV unsigned short f2bf(float f){ union{float f; unsigned int i;} v; v.f=f; unsigned int x=v.i;
  return (unsigned short)((x + 0x7fffu + ((x>>16)&1u)) >> 16); }

// ---------------------------------------------------------------------------
// Zero the padded-border prefix (th..gt2). MUST run before k_prep_all.
// ---------------------------------------------------------------------------
__global__ void k_zero(uint4* __restrict__ p, int n16)
{
  int idx = blockIdx.x*256 + threadIdx.x;
  if (idx < n16) p[idx] = uint4{0,0,0,0};
}

// ---------------------------------------------------------------------------
// prep bodies (shared LDS buffer, routed by block range in k_prep_all).
// ---------------------------------------------------------------------------
DEV void prep1_body(int bid, const float* __restrict__ x,
                    const float* __restrict__ wt, const float* __restrict__ bt,
                    const float* __restrict__ wp, const float* __restrict__ bp,
                    const float* __restrict__ wg, const float* __restrict__ bg,
                    unsigned short* __restrict__ th, unsigned short* __restrict__ ph,
                    float* __restrict__ gt, char* smemc)
{
  float (*red)[64][48] = (float(*)[64][48])smemc;
  float* wl = (float*)(smemc + 36864);     // wt[1024] | wp[1024] | wg[1024]
  int tid = threadIdx.x;
  for (int u = tid; u < 768; u += 256) {
    float4 v;
    if (u < 256) v = ((const float4*)wt)[u];
    else if (u < 512) v = ((const float4*)wp)[u-256];
    else v = ((const float4*)wg)[u-512];
    ((float4*)wl)[u] = v;
  }
  __syncthreads();
  int grp = tid >> 6, pixl = tid & 63;
  int pix = bid*64 + pixl;                 // [0, 32768)
  int b = pix >> 14, p = pix & 16383, i = p >> 7, j = p & 127;
  float a[48];
#pragma unroll
  for (int c=0;c<48;++c) a[c]=0.f;
  const float* xb = x + (size_t)b*64*16384 + p;
#pragma unroll
  for (int c4=0; c4<4; ++c4) {
    int cc = grp*16 + c4*4;
    float xv[4];
#pragma unroll
    for (int u=0;u<4;++u) xv[u] = xb[(size_t)(cc+u)*16384];
#pragma unroll
    for (int ic=0;ic<16;++ic) {
      float4 w0 = *(const float4*)(wl + ic*64 + cc);
      float4 w1 = *(const float4*)(wl + 1024 + ic*64 + cc);
      float4 w2 = *(const float4*)(wl + 2048 + ic*64 + cc);
      a[ic]    += xv[0]*w0.x + xv[1]*w0.y + xv[2]*w0.z + xv[3]*w0.w;
      a[16+ic] += xv[0]*w1.x + xv[1]*w1.y + xv[2]*w1.z + xv[3]*w1.w;
      a[32+ic] += xv[0]*w2.x + xv[1]*w2.y + xv[2]*w2.z + xv[3]*w2.w;
    }
  }
  if (grp) {
#pragma unroll
    for (int c=0;c<48;++c) red[grp-1][pixl][c] = a[c];
  }
  __syncthreads();
  if (grp == 0) {
#pragma unroll
    for (int c=0;c<48;++c) a[c] += red[0][pixl][c] + red[1][pixl][c] + red[2][pixl][c];
    const float TEMPC = 14.426950408889634f;
    unsigned short o[16];
#pragma unroll
    for (int ic=0;ic<16;++ic) o[ic] = f2bf((a[ic]+bt[ic])*TEMPC);
    uint4* d0 = (uint4*)(th + ((size_t)(b*134 + i+3)*136 + (j+3))*16);
    d0[0]=*(uint4*)&o[0]; d0[1]=*(uint4*)&o[8];
#pragma unroll
    for (int ic=0;ic<16;++ic) o[ic] = f2bf(a[16+ic]+bp[ic]);
    uint4* d1 = (uint4*)(ph + ((size_t)(b*134 + i+3)*136 + (j+3))*16);
    d1[0]=*(uint4*)&o[0]; d1[1]=*(uint4*)&o[8];
#pragma unroll
    for (int ic=0;ic<16;++ic)
      gt[(((size_t)b*16+ic)*134 + i+3)*136 + (j+3)] = a[32+ic]+bg[ic];
  }
}

DEV void conv2_body(int bid, const float* __restrict__ x,
                    const float* __restrict__ wp, const float* __restrict__ bp,
                    const float* __restrict__ wg, const float* __restrict__ bg,
                    unsigned short* __restrict__ phi, float* __restrict__ gt, char* smemc)
{
  float (*red)[64][32] = (float(*)[64][32])smemc;
  float* wl = (float*)(smemc + 24576);     // wp[4096] | wg[4096]
  int tid = threadIdx.x;
  for (int u = tid; u < 2048; u += 256) {
    float4 v = (u < 1024) ? ((const float4*)wp)[u] : ((const float4*)wg)[u-1024];
    ((float4*)wl)[u] = v;
  }
  __syncthreads();
  int grp = tid >> 6, pixl = tid & 63;
  int pix = bid*64 + pixl;                 // [0, 8192)
  int b = pix >> 12, p = pix & 4095, i = p >> 6, j = p & 63;
  float a[32];
#pragma unroll
  for (int c=0;c<32;++c) a[c]=0.f;
  const float* xb = x + (size_t)b*64*16384 + (i*2)*128 + j*2;
#pragma unroll
  for (int c0=0; c0<16; ++c0) {
    int cc = grp*16 + c0;
    const float* xp = xb + (size_t)cc*16384;
    float xv[4];
    xv[0]=xp[0]; xv[1]=xp[1]; xv[2]=xp[128]; xv[3]=xp[129];
#pragma unroll
    for (int ic=0;ic<16;++ic) {
      float4 w0 = *(const float4*)(wl + (ic*64+cc)*4);
      float4 w1 = *(const float4*)(wl + 4096 + (ic*64+cc)*4);
      a[ic]    += xv[0]*w0.x + xv[1]*w0.y + xv[2]*w0.z + xv[3]*w0.w;
      a[16+ic] += xv[0]*w1.x + xv[1]*w1.y + xv[2]*w1.z + xv[3]*w1.w;
    }
  }
  if (grp) {
#pragma unroll
    for (int c=0;c<32;++c) red[grp-1][pixl][c] = a[c];
  }
  __syncthreads();
  if (grp == 0) {
#pragma unroll
    for (int c=0;c<32;++c) a[c] += red[0][pixl][c] + red[1][pixl][c] + red[2][pixl][c];
    unsigned short o[16];
#pragma unroll
    for (int ic=0;ic<16;++ic) o[ic] = f2bf(a[ic]+bp[ic]);
    uint4* d1 = (uint4*)(phi + ((size_t)(b*70 + i+3)*72 + (j+3))*16);
    d1[0]=*(uint4*)&o[0]; d1[1]=*(uint4*)&o[8];
#pragma unroll
    for (int ic=0;ic<16;++ic)
      gt[(((size_t)b*16+ic)*70 + i+3)*72 + (j+3)] = a[16+ic]+bg[ic];
  }
}

DEV void conv4_body(int bid, const float* __restrict__ x,
                    const float* __restrict__ wp, const float* __restrict__ wg,
                    const float* __restrict__ bp, const float* __restrict__ bg,
                    unsigned short* __restrict__ phi, float* __restrict__ gt, char* smemc)
{
  float (*xs)[1028] = (float(*)[1028])smemc;
  int tid = threadIdx.x;
  int pix0 = bid*8;                        // [0,2048) step 8
  for (int idx = tid; idx < 8*1024; idx += 256) {
    int pl = idx >> 10, e = idx & 1023;
    int pix = pix0 + pl; int b = pix >> 10, p = pix & 1023, i = p >> 5, j = p & 31;
    int cc = e >> 4, a_ = (e >> 2) & 3, bb = e & 3;
    xs[pl][e] = x[(((size_t)b*64+cc)*128 + i*4+a_)*128 + j*4+bb];
  }
  __syncthreads();
  int pp = tid >> 5, icp = tid & 31;
  int pix = pix0 + pp; int b = pix >> 10, p = pix & 1023, i = p >> 5, j = p & 31;
  int ic = icp & 15;
  const float* wsrc = ((icp < 16) ? wp : wg) + ic*1024;
  float acc = 0.f;
#pragma unroll 8
  for (int k4=0; k4<256; ++k4) {
    float4 xv = *(const float4*)(&xs[pp][k4*4]);
    float4 wv = *(const float4*)(wsrc + k4*4);
    acc += xv.x*wv.x + xv.y*wv.y + xv.z*wv.z + xv.w*wv.w;
  }
  if (icp < 16)
    phi[(((size_t)(b*38 + i+3)*40) + (j+3))*16 + ic] = f2bf(acc + bp[ic]);
  else
    gt[(((size_t)b*16+ic)*38 + i+3)*40 + (j+3)] = acc + bg[ic];
}

__global__ void k_prep_all(const float* __restrict__ x,
                           const float* __restrict__ wt, const float* __restrict__ bt,
                           const float* __restrict__ wp0, const float* __restrict__ bp0,
                           const float* __restrict__ wg0, const float* __restrict__ bg0,
                           const float* __restrict__ wp1, const float* __restrict__ bp1,
                           const float* __restrict__ wg1, const float* __restrict__ bg1,
                           const float* __restrict__ wp2, const float* __restrict__ wg2,
                           const float* __restrict__ bp2, const float* __restrict__ bg2,
                           unsigned short* __restrict__ th, unsigned short* __restrict__ ph0,
                           float* __restrict__ gt0,
                           unsigned short* __restrict__ ph1, float* __restrict__ gt1,
                           unsigned short* __restrict__ ph2, float* __restrict__ gt2)
{
  __shared__ __align__(16) char smem[57344];
  int bid = blockIdx.x;
  if (bid < 512)      prep1_body(bid, x, wt,bt, wp0,bp0, wg0,bg0, th, ph0, gt0, smem);
  else if (bid < 640) conv2_body(bid-512, x, wp1,bp1, wg1,bg1, ph1, gt1, smem);
  else                conv4_body(bid-640, x, wp2,wg2, bp2, bg2, ph2, gt2, smem);
}

// ---------------------------------------------------------------------------
// V tile buffer: g8b[b][sh][y][xb][c][32] bf16 (1KB tile per (sh,y,xb)).
// ---------------------------------------------------------------------------
template<int HP, int WX, int HS>
DEV void shift_body(int idx, const float* __restrict__ gt, unsigned short* __restrict__ g8b)
{
  const int XB = HS/32;
  int xkg = idx & 3;
  int c = (idx >> 2) & 15;
  int t = idx >> 6;
  int xb = t % XB; t /= XB;
  int y = t % HP; t /= HP;
  int sh = t & 7; int b = t >> 3;
  const float* src = gt + (((size_t)b*16+c)*HP + y)*WX + xb*32 + xkg*8 + sh;
  unsigned short o[8];
#pragma unroll
  for (int j=0;j<8;++j) o[j] = f2bf(src[j]);
  unsigned short* dst = g8b + ((((size_t)(b*8+sh)*HP + y)*XB + xb)*16 + c)*32 + xkg*8;
  *(uint4*)dst = *(uint4*)&o[0];
}

__global__ void k_shift_all(const float* __restrict__ gt0, const float* __restrict__ gt1,
                            const float* __restrict__ gt2,
                            unsigned short* __restrict__ g80, unsigned short* __restrict__ g81,
                            unsigned short* __restrict__ g82)
{
  const int T0 = 2*8*134*4*16*4;           // 548864
  const int T1 = 2*8*70*2*16*4;            // 143360
  const int T2 = 2*8*38*1*16*4;            // 38912
  int idx = blockIdx.x*256 + threadIdx.x;
  if (idx < T0) { shift_body<134,136,128>(idx, gt0, g80); return; }
  idx -= T0;
  if (idx < T1) { shift_body<70,72,64>(idx, gt1, g81); return; }
  idx -= T1;
  if (idx < T2) { shift_body<38,40,32>(idx, gt2, g82); }
}

// ---------------------------------------------------------------------------
// Flash attention body. RING=true (s=1 only): phi staged in an 8-row LDS
// ring (slot = row & 7); prologue stages 8 rows, each iter stages the 2 NEW
// rows via global_load_lds overlapped under PV -> QK is pure LDS + MFMA.
// RING=false: round-20 rotated pipeline (phi from global), P double-buffer.
// LDS (RING): theta 30464 | ring 34816 | P 16384 = 81664 (2 blocks/CU).
// ---------------------------------------------------------------------------
template<int HS, int LG, int HP, int WX, int CK, int NCH, bool RING>
DEV void attn_body(int bid, int slot0,
                   const unsigned short* __restrict__ th,
                   const unsigned short* __restrict__ phi,
                   const unsigned short* __restrict__ g8b,
                   unsigned short* __restrict__ accP, float* __restrict__ lP, char* smem)
{
  const int PO   = 30464;                  // !RING: P dbuf base
  const int PHI0 = 30464;                  // RING: phi ring base
  const int PO_R = 65280;                  // RING: P base (single)
  int tid = threadIdx.x;
  int w = tid >> 6, lane = tid & 63, l15 = lane & 15, g = lane >> 4;
  int chunk, b, qt;
  if (NCH == 8) { chunk = bid & 7; b = (bid >> 3) & 1; qt = bid >> 4; }
  else          { chunk = bid & 3; b = (bid >> 2) & 1; qt = bid >> 3; }
  int q0 = qt * 32;
  int slot = slot0 + chunk;

  const char* thB  = (const char*)th  + (size_t)b*134*136*32;
  const char* phiB = (const char*)phi + (size_t)b*HP*WX*32;

  for (int u = tid; u < 7*136*2; u += 512) {
    int half = u & 1; int cu = (u >> 1) % 136; int r = (u >> 1) / 136;
    uint4 v = *(const uint4*)(thB + (((4*qt+2+r)*136 + cu)*32 + half*16));
    int la = (((r*136 + cu)*32) + half*16) ^ (((cu >> 2) & 7) << 4);
    *(uint4*)(smem + la) = v;
  }
  __syncthreads();

  f32x4 acc[2][7];
#pragma unroll
  for (int rt=0;rt<2;++rt)
#pragma unroll
    for (int et=0;et<7;++et) acc[rt][et] = f32x4{0.f,0.f,0.f,0.f};
  float lacc[2][4];
#pragma unroll
  for (int rt=0;rt<2;++rt)
#pragma unroll
    for (int r=0;r<4;++r) lacc[rt][r] = 0.f;

  const int XBv = HS/32;
  const char* g8B  = (const char*)g8b + (size_t)b*8*HP*XBv*1024;
  const int EPL = HP*XBv*1024;
  int laneVb = l15*64 + g*16;
  int xrP = (l15 & 7) << 4;
  int colb = 4*l15 + 2;
  int hb = (g & 1) << 4;
  const bf16x8 ZV = {0,0,0,0,0,0,0,0};
  const int ITERS = CK/256;
  const float SHIFT = 64.0f, CLAMP = 120.0f;

  // stage one phi row (4352B = 272x16B) into ring slot (row & 7)
  auto stage_row = [&](int row) {
    int slotr = row & 7;
    const char* src = phiB + (size_t)row*WX*32;
    int w2 = tid >> 6;
    char* dstb = smem + PHI0 + slotr*4352 + w2*1024;   // wave-uniform base
    if (tid < 272)
      __builtin_amdgcn_global_load_lds(
        (const __attribute__((address_space(1))) unsigned int*)(src + tid*16),
        (__attribute__((address_space(3))) unsigned int*)dstb, 16, 0, 0);
  };

  auto QK = [&](int it) {
    int k0 = chunk*CK + it*256;
    int po = RING ? PO_R : (PO + ((it & 1) << 14));
    f32x4 sc[2][2];
#pragma unroll
    for (int rt=0;rt<2;++rt){ sc[rt][0]=f32x4{0.f,0.f,0.f,0.f}; sc[rt][1]=f32x4{0.f,0.f,0.f,0.f}; }
    int kr_w = (k0 + w*32) >> LG;
    int kc_w = (w*32) & (HS-1);
    int base0 = (kr_w*WX + kc_w + l15)*32 + hb;
#pragma unroll
    for (int ks=0; ks<25; ++ks) {
      int p0 = 2*ks;
      int p1 = (2*ks+1 > 48) ? 48 : 2*ks+1;
      int dr0 = p0/7, dc0 = p0%7;
      int dr1 = p1/7, dc1 = p1%7;
      int c0 = colb + dc0, c1 = colb + dc1;
      int la0 = ((dr0*136 + c0)*32 + hb) ^ (((c0 >> 2) & 7) << 4);
      int la1 = ((dr1*136 + c1)*32 + hb) ^ (((c1 >> 2) & 7) << 4);
      int laA = (g & 2) ? la1 : la0;
      bf16x8 a0 = *(const bf16x8*)(smem + laA);
      bf16x8 a1 = *(const bf16x8*)(smem + laA + 2048);
      if (ks == 24) {
        bool z = (g & 2) != 0;
        a0 = z ? ZV : a0; a1 = z ? ZV : a1;
      }
      bf16x8 b0, b1;
      if constexpr (RING) {
        int laB0 = ((kr_w + dr0) & 7)*4352 + (kc_w + l15 + dc0)*32 + hb;
        int laB1 = ((kr_w + dr1) & 7)*4352 + (kc_w + l15 + dc1)*32 + hb;
        int laB = (g & 2) ? laB1 : laB0;
        b0 = *(const bf16x8*)(smem + PHI0 + laB);
        b1 = *(const bf16x8*)(smem + PHI0 + laB + 512);
      } else {
        int KB0 = (dr0*WX + dc0)*32;
        int KB1 = (dr1*WX + dc1)*32;
        int selB = (g & 2) ? KB1 : KB0;
        b0 = *(const bf16x8*)(phiB + base0 + selB);
        b1 = *(const bf16x8*)(phiB + base0 + 512 + selB);
      }
      sc[0][0] = __builtin_amdgcn_mfma_f32_16x16x32_bf16(a0, b0, sc[0][0], 0,0,0);
      sc[0][1] = __builtin_amdgcn_mfma_f32_16x16x32_bf16(a0, b1, sc[0][1], 0,0,0);
      sc[1][0] = __builtin_amdgcn_mfma_f32_16x16x32_bf16(a1, b0, sc[1][0], 0,0,0);
      sc[1][1] = __builtin_amdgcn_mfma_f32_16x16x32_bf16(a1, b1, sc[1][1], 0,0,0);
    }
#pragma unroll
    for (int rt=0;rt<2;++rt) {
#pragma unroll
      for (int r=0;r<4;++r) {
        float pa = __builtin_amdgcn_exp2f(fminf(sc[rt][0][r] - SHIFT, CLAMP));
        float pb = __builtin_amdgcn_exp2f(fminf(sc[rt][1][r] - SHIFT, CLAMP));
        lacc[rt][r] += pa + pb;
        int q_ = rt*16 + g*4 + r;
        int offa = q_*512 + (w*32 + l15)*2;      offa ^= (q_&7)<<4;
        int offb = q_*512 + (w*32 + 16 + l15)*2; offb ^= (q_&7)<<4;
        *(unsigned short*)(smem + po + offa) = f2bf(pa);
        *(unsigned short*)(smem + po + offb) = f2bf(pb);
      }
    }
  };

  auto PV = [&](int it) {
    if (w >= 7) return;
    int k0 = chunk*CK + it*256;
    int po = RING ? PO_R : (PO + ((it & 1) << 14));
#pragma unroll
    for (int ks2=0; ks2<8; ++ks2) {
      int kk = k0 + ks2*32;
      int krv = kk >> LG;
      int kcb = kk & (HS-1);
      bf16x8 pf[2];
#pragma unroll
      for (int rt=0;rt<2;++rt) {
        int off = (rt*16 + l15)*512 + ks2*64 + g*16;
        off ^= xrP;
        pf[rt] = *(const bf16x8*)(smem + po + off);
      }
      int vb = ((krv + w)*XBv + (kcb >> 5))*1024 + laneVb;
      bf16x8 vf[7];
#pragma unroll
      for (int et=0;et<7;++et) {
        u32x4 t0 = __builtin_nontemporal_load((const u32x4*)(g8B + vb + et*EPL));
        vf[et] = *(bf16x8*)&t0;
      }
      __builtin_amdgcn_s_setprio(1);
#pragma unroll
      for (int rt=0;rt<2;++rt)
#pragma unroll
        for (int et=0;et<7;++et)
          acc[rt][et] = __builtin_amdgcn_mfma_f32_16x16x32_bf16(pf[rt], vf[et], acc[rt][et], 0,0,0);
      __builtin_amdgcn_s_setprio(0);
    }
  };

  if constexpr (RING) {
    // prologue: stage the full 8-row window of iter 0
    int r0 = (chunk*CK) >> LG;
#pragma unroll
    for (int rr = 0; rr < 8; ++rr) stage_row(r0 + rr);
    __syncthreads();                       // drains vmcnt -> ring ready
#pragma unroll 1
    for (int it = 0; it < ITERS; ++it) {
      QK(it);                              // pure LDS
      __syncthreads();                     // B: P ready; phi(t) reads done
      if (it+1 < ITERS) {
        int nr = ((chunk*CK + (it+1)*256) >> LG) + 6;
        stage_row(nr);                     // 2 new rows for t+1,
        stage_row(nr+1);                   // overwrite slots QK(t) just freed
      }
      PV(it);                              // overlaps staging DMA
      __syncthreads();                     // A: staging drained; P free
    }
  } else {
    QK(0);
    __syncthreads();
#pragma unroll 1
    for (int it = 1; it < ITERS; ++it) {
      PV(it-1);
      QK(it);
      __syncthreads();
    }
    PV(ITERS-1);
  }

  if (w < 7) {
    unsigned short* accB = accP +
      ((((size_t)(slot*2 + b)*32 + qt)*7 + w)*14)*256;
#pragma unroll
    for (int rt=0;rt<2;++rt)
#pragma unroll
      for (int et=0;et<7;++et)
#pragma unroll
        for (int r=0;r<4;++r)
          __builtin_nontemporal_store(f2bf(acc[rt][et][r]),
            &accB[(size_t)(rt*7 + et)*256 + r*64 + lane]);
  }
#pragma unroll
  for (int st=1; st<16; st<<=1)
#pragma unroll
    for (int rt=0;rt<2;++rt)
#pragma unroll
      for (int r=0;r<4;++r) lacc[rt][r] += __shfl_xor(lacc[rt][r], st);
  if (l15 == 0) {
#pragma unroll
    for (int rt=0;rt<2;++rt)
#pragma unroll
      for (int r=0;r<4;++r)
        lP[((size_t)((slot*2 + b)*8 + w) << 10) + q0 + rt*16 + g*4 + r] = lacc[rt][r];
  }
}

__global__ void __launch_bounds__(512, 2)
k_attn_all(const unsigned short* __restrict__ th,
           const unsigned short* __restrict__ ph0, const unsigned short* __restrict__ ph1,
           const unsigned short* __restrict__ ph2,
           const unsigned short* __restrict__ g80, const unsigned short* __restrict__ g81,
           const unsigned short* __restrict__ g82,
           unsigned short* __restrict__ accP, float* __restrict__ lP)
{
  __shared__ __align__(16) char smem[81664];
  int bid = blockIdx.x;
  if (bid < 512)       attn_body<128,7,134,136,2048,8,true> (bid,      0,  th, ph0, g80, accP, lP, smem);
  else if (bid < 1024) attn_body<64,6,70,72,512,8,false>    (bid-512,  8,  th, ph1, g81, accP, lP, smem);
  else                 attn_body<32,5,38,40,256,4,false>    (bid-1024, 16, th, ph2, g82, accP, lP, smem);
}

// ---------------------------------------------------------------------------
// lG[sc][b*1024+q] = sum over chunks and waves of lP (all 3 scales)
// ---------------------------------------------------------------------------
__global__ void k_comb1_all(const float* __restrict__ lP, float* __restrict__ lG)
{
  int idx = blockIdx.x*256 + threadIdx.x;
  if (idx >= 3*2048) return;
  int sc = idx >> 11, i2 = idx & 2047;
  int b = i2 >> 10, q = i2 & 1023;
  const int NCH[3] = {8,8,4}, S0[3] = {0,8,16};
  float l = 0.f;
  for (int c=0;c<NCH[sc];++c)
#pragma unroll
    for (int w=0;w<8;++w)
      l += lP[((size_t)(((S0[sc]+c)*2 + b)*8 + w) << 10) + q];
  lG[idx] = l;
}

// ---------------------------------------------------------------------------
// Coalesced comb2 (unchanged)
// ---------------------------------------------------------------------------
__global__ void k_comb2_all(const unsigned short* __restrict__ accP,
                            const float* __restrict__ lG, float* __restrict__ yvfP)
{
  int t8 = blockIdx.x*256 + threadIdx.x;
  if (t8 >= 3*200704) return;
  int sc = t8 / 200704;
  int rem = t8 - sc*200704;
  int e = rem*8;
  int low = e & 255;
  int r = low >> 6, g = (low >> 4) & 3;
  int tile = e >> 8;
  int et = tile % 7; int tt = tile / 7;
  int rt = tt & 1; tt >>= 1;
  int w = tt % 7; tt /= 7;
  int qt = tt & 31; int b = tt >> 5;
  int bq = (b << 10) + qt*32 + rt*16 + g*4 + r;
  const int NCH[3] = {8,8,4}, S0[3] = {0,8,16};
  float s[8];
#pragma unroll
  for (int u=0;u<8;++u) s[u]=0.f;
  for (int ch=0; ch<NCH[sc]; ++ch) {
    const unsigned short* ap = accP + (size_t)(S0[sc]+ch)*1605632 + e;
    u32x4 v = __builtin_nontemporal_load((const u32x4*)ap);
    const unsigned short* pv = (const unsigned short*)&v;
#pragma unroll
    for (int u=0;u<8;++u) s[u] += bf2f(pv[u]);
  }
  float inv = 1.0f / lG[sc*2048 + bq];
  float* dst = yvfP + (size_t)sc*1605632 + e;
  float4 o0, o1;
  o0.x=s[0]*inv; o0.y=s[1]*inv; o0.z=s[2]*inv; o0.w=s[3]*inv;
  o1.x=s[4]*inv; o1.y=s[5]*inv; o1.z=s[6]*inv; o1.w=s[7]*inv;
  *(float4*)dst = o0; *(float4*)(dst+4) = o1;
}

// ---------------------------------------------------------------------------
// fold from permuted yvfP + /mask + conv1x1(w_out)+b_out + x (channel-split)
// ---------------------------------------------------------------------------
__global__ void k_foldfinal(const float* __restrict__ yvfP, const float* __restrict__ wo,
                            const float* __restrict__ bo, const float* __restrict__ x,
                            float* __restrict__ out)
{
  __shared__ float wl[32*48];
  int half = blockIdx.x >> 7;
  int pixb = blockIdx.x & 127;
  for (int t = threadIdx.x; t < 32*48; t += 256) wl[t] = wo[half*32*48 + t];
  __syncthreads();
  int idx = pixb*256 + threadIdx.x;
  int j = idx & 127; int t = idx >> 7; int i = t & 127; int b = t >> 7;

  int drs[2], qis[2], cnti=0;
  int dcs[2], qjs[2], cntj=0;
#pragma unroll
  for (int dr=0; dr<7; ++dr) {
    int tr = i + 3 - dr;
    if (tr >= 0 && (tr & 3) == 0 && (tr >> 2) < 32) { drs[cnti]=dr; qis[cnti]=tr>>2; ++cnti; }
  }
#pragma unroll
  for (int dc=0; dc<7; ++dc) {
    int tc = j + 3 - dc;
    if (tc >= 0 && (tc & 3) == 0 && (tc >> 2) < 32) { dcs[cntj]=dc; qjs[cntj]=tc>>2; ++cntj; }
  }
  float inv = 1.0f / (float)(cnti*cntj);

  float y[48];
#pragma unroll
  for (int sc=0; sc<3; ++sc) {
    const float* yb = yvfP + (size_t)sc*1605632;
    float a[16];
#pragma unroll
    for (int c=0;c<16;++c) a[c]=0.f;
    for (int u=0; u<cnti; ++u) {
      for (int v=0; v<cntj; ++v) {
        int q = qis[u]*32 + qjs[v];
        int qt = q >> 5, rt = (q >> 4) & 1, gg = (q >> 2) & 3, rr = q & 3;
        int off = ((((b*32 + qt)*7 + drs[u])*2 + rt)*7 + dcs[v])*256 + rr*64 + gg*16;
        const float* src = yb + off;
        float4 v0 = *(const float4*)(src);
        float4 v1 = *(const float4*)(src+4);
        float4 v2 = *(const float4*)(src+8);
        float4 v3 = *(const float4*)(src+12);
        a[0]+=v0.x; a[1]+=v0.y; a[2]+=v0.z; a[3]+=v0.w;
        a[4]+=v1.x; a[5]+=v1.y; a[6]+=v1.z; a[7]+=v1.w;
        a[8]+=v2.x; a[9]+=v2.y; a[10]+=v2.z; a[11]+=v2.w;
        a[12]+=v3.x; a[13]+=v3.y; a[14]+=v3.z; a[15]+=v3.w;
      }
    }
#pragma unroll
    for (int c=0;c<16;++c) y[sc*16+c] = a[c]*inv;
  }

  const float* xb = x + (size_t)b*64*16384 + i*128 + j;
  float* ob = out + (size_t)b*64*16384 + i*128 + j;
  for (int o=0;o<32;++o) {
    int oc = half*32 + o;
    float s = bo[oc];
#pragma unroll
    for (int c=0;c<48;++c) s += y[c]*wl[o*48+c];
    ob[(size_t)oc*16384] = s + xb[(size_t)oc*16384];
  }
}

// ---------------------------------------------------------------------------
extern "C" void kernel_launch(void* const* d_in, const int* in_sizes, int n_in,
                              void* d_out, int out_size, void* d_ws, size_t ws_size,
                              hipStream_t stream)
{
  const float* x  = (const float*)d_in[0];
  const float* wt = (const float*)d_in[1];
  const float* bt = (const float*)d_in[2];
  const float* wp0= (const float*)d_in[3];
  const float* bp0= (const float*)d_in[4];
  const float* wg0= (const float*)d_in[5];
  const float* bg0= (const float*)d_in[6];
  const float* wp1= (const float*)d_in[7];
  const float* bp1= (const float*)d_in[8];
  const float* wg1= (const float*)d_in[9];
  const float* bg1= (const float*)d_in[10];
  const float* wp2= (const float*)d_in[11];
  const float* bp2= (const float*)d_in[12];
  const float* wg2= (const float*)d_in[13];
  const float* bg2= (const float*)d_in[14];
  const float* wo = (const float*)d_in[15];
  const float* bo = (const float*)d_in[16];
  float* out = (float*)d_out;
  (void)in_sizes; (void)n_in; (void)out_size; (void)ws_size;

  char* ws = (char*)d_ws;
  size_t off = 0;
  auto alloc = [&](size_t bytes)->char* { char* p = ws + off; off += (bytes + 255) & ~(size_t)255; return p; };
  unsigned short* th  = (unsigned short*)alloc(2ull*134*136*16*2);
  unsigned short* ph0 = (unsigned short*)alloc(2ull*134*136*16*2);
  unsigned short* ph1 = (unsigned short*)alloc(2ull*70*72*16*2);
  unsigned short* ph2 = (unsigned short*)alloc(2ull*38*40*16*2);
  float* gt0 = (float*)alloc(2ull*16*134*136*4);
  float* gt1 = (float*)alloc(2ull*16*70*72*4);
  float* gt2 = (float*)alloc(2ull*16*38*40*4);
  size_t zeroBytes = off;                      // th..gt2 contiguous prefix
  unsigned short* g80 = (unsigned short*)alloc(2ull*8*134*4*512*2);
  unsigned short* g81 = (unsigned short*)alloc(2ull*8*70*2*512*2);
  unsigned short* g82 = (unsigned short*)alloc(2ull*8*38*1*512*2);
  float* lP  = (float*)alloc(20ull*2*8*1024*4);
  float* lG  = (float*)alloc(3ull*2048*4);
  unsigned short* accP = (unsigned short*)alloc(20ull*2048*784*2);
  float* yvfP = (float*)alloc(3ull*2048*784*4);

  int n16 = (int)(zeroBytes/16);
  k_zero<<<(n16+255)/256,256,0,stream>>>((uint4*)ws, n16);
  k_prep_all<<<896,256,0,stream>>>(x, wt,bt, wp0,bp0,wg0,bg0, wp1,bp1,wg1,bg1,
                                   wp2,wg2, bp2,bg2, th,ph0,gt0, ph1,gt1, ph2,gt2);
  k_shift_all<<<(548864+143360+38912+255)/256,256,0,stream>>>(gt0,gt1,gt2, g80,g81,g82);
  k_attn_all<<<1280,512,0,stream>>>(th, ph0,ph1,ph2, g80,g81,g82, accP, lP);
  k_comb1_all<<<(3*2048+255)/256,256,0,stream>>>(lP, lG);
  k_comb2_all<<<(3*200704+255)/256,256,0,stream>>>(accP, lG, yvfP);
  k_foldfinal<<<256,256,0,stream>>>(yvfP, wo, bo, x, out);
}